// Round 7
// baseline (644.698 us; speedup 1.0000x reference)
//
#include <hip/hip_runtime.h>
#include <hip/hip_bf16.h>

typedef unsigned short u16;
typedef __attribute__((ext_vector_type(8))) _Float16 half8;  // 8 fp16 in 4 VGPRs
typedef __attribute__((ext_vector_type(8))) unsigned short u16x8;
typedef __attribute__((ext_vector_type(16))) float f32x16;

static __device__ __forceinline__ u16 f2h(float v) {
  return __builtin_bit_cast(u16, (_Float16)v);
}
static __device__ __forceinline__ float h2f(u16 u) {
  return (float)__builtin_bit_cast(_Float16, u);
}

// async global->LDS, 16B per lane. LDS dest = wave-uniform base + lane*16.
static __device__ __forceinline__ void gll16(const void* g, void* l) {
  __builtin_amdgcn_global_load_lds(
      (const __attribute__((address_space(1))) unsigned int*)g,
      (__attribute__((address_space(3))) unsigned int*)l, 16, 0, 0);
}

template <int N>
static __device__ __forceinline__ void wait_vm() {
  if constexpr (N == 0) asm volatile("s_waitcnt vmcnt(0)" ::: "memory");
  else if constexpr (N == 4) asm volatile("s_waitcnt vmcnt(4)" ::: "memory");
  else if constexpr (N == 6) asm volatile("s_waitcnt vmcnt(6)" ::: "memory");
  else asm volatile("s_waitcnt vmcnt(8)" ::: "memory");
}

// ---------------------------------------------------------------------------
// gemm_bt: C[m][n] = sum_k A[m][k] * B[n][k]  (both K-contiguous, fp16).
// 128x128 tile, BK=32, 4 waves (2x2), wave tile 64x64.
// r7: inner compute switched to v_mfma_f32_32x32x16_f16 (2x2 32x32 tiles per
// wave, 8 MFMA/K-step vs 16) -- 32x32 pipe is ~15% faster at ubench level
// and halves issue count. Input frag map: row = lane&31, k-chunk = lane>>5
// (8 contiguous k) -- analog of the verified 16x16 map. C/D map (HW-verified
// m74/m101): col = lane&31, row = (reg&3) + 8*(reg>>2) + 4*(lane>>5).
// LDS slot-XOR swizzle (both-sides, rule 21): staging source chunk
// kc^(r4&3) with linear LDS dest; reads XOR slot with row&3. Keeps the
// 32-row read pattern at the 16x16 conflict level.
// NBUF=2 for L2/L3-resident z==1 GEMMs; NBUF=3 counted-vmcnt for z>1.
// XCD-chunked swizzle only when z>1 [r2: on z==1 conv it cost +32MB FETCH].
// EPI: 0 = fp32 store; 1 = bias(m) + split2-fp16 store (Ch,Cl);
//      2 = fp32 + fp16 store; 3 = bias(n) + fp16 store; 4 = fp16 store
// ---------------------------------------------------------------------------
template <int NBUF, bool ASPLIT, bool BSPLIT, int EPI>
__global__ __launch_bounds__(256) void gemm_bt(
    const u16* __restrict__ A, const u16* __restrict__ Al,
    const u16* __restrict__ B, const u16* __restrict__ Bl,
    float* __restrict__ Cf, u16* __restrict__ Ch, u16* __restrict__ Cl,
    const float* __restrict__ bias0, const float* __restrict__ bias1,
    int biasSplit, int K, int lda, int ldb, int ldc,
    long long sA, long long sB, long long sC) {
  __shared__ __align__(16) u16 smA[NBUF][(ASPLIT ? 2 : 1) * 128 * 32];
  __shared__ __align__(16) u16 smB[NBUF][(BSPLIT ? 2 : 1) * 128 * 32];
  constexpr int G = 4 + (ASPLIT ? 2 : 0) + (BSPLIT ? 2 : 0);  // loads per stage
  constexpr int PD = NBUF - 1;                                 // prefetch depth

  const int tid = threadIdx.x;
  const int wave = tid >> 6, lane = tid & 63;
  const int wr = wave >> 1, wc = wave & 1;

  const int gx = gridDim.x, gy = gridDim.y;
  int bx, by;
  long long z;
  if (gridDim.z > 1) {
    const int nwg = gx * gy * (int)gridDim.z;
    const int bid = (int)blockIdx.x + gx * ((int)blockIdx.y + gy * (int)blockIdx.z);
    const int w = (bid & 7) * (nwg >> 3) + (bid >> 3);
    bx = w % gx;
    const int rem = w / gx;
    by = rem % gy;
    z = rem / gy;
  } else {
    bx = blockIdx.x;
    by = blockIdx.y;
    z = 0;
  }

  A += z * sA;
  B += z * sB;
  if (ASPLIT) Al += z * sA;
  if (BSPLIT) Bl += z * sB;
  const long long tM = (long long)by * 128;
  const long long tN = (long long)bx * 128;
  const int r4 = lane >> 2, kc = lane & 3;
  const int kcs = kc ^ (r4 & 3);  // swizzled source chunk (involution)

  const long long arow0 = (tM + wave * 16 + r4) * (long long)lda + kcs * 8;
  const long long arow1 = arow0 + 64LL * lda;
  const long long brow0 = (tN + wave * 16 + r4) * (long long)ldb + kcs * 8;
  const long long brow1 = brow0 + 64LL * ldb;

  auto stage = [&](int bf, long long ko) {
    u16* dA = &smA[bf][wave * 512];
    u16* dB = &smB[bf][wave * 512];
    gll16(A + arow0 + ko, dA);
    gll16(A + arow1 + ko, dA + 2048);
    gll16(B + brow0 + ko, dB);
    gll16(B + brow1 + ko, dB + 2048);
    if constexpr (ASPLIT) {
      gll16(Al + arow0 + ko, dA + 4096);
      gll16(Al + arow1 + ko, dA + 4096 + 2048);
    }
    if constexpr (BSPLIT) {
      gll16(Bl + brow0 + ko, dB + 4096);
      gll16(Bl + brow1 + ko, dB + 4096 + 2048);
    }
  };

  f32x16 acc[2][2];
#pragma unroll
  for (int i = 0; i < 2; i++)
#pragma unroll
    for (int j = 0; j < 2; j++)
#pragma unroll
      for (int p = 0; p < 16; p++) acc[i][j][p] = 0.f;

  const int l31 = lane & 31, hi = lane >> 5;
  const int nk = K >> 5;

  stage(0, 0);
  if constexpr (PD == 2) {
    if (nk > 1) stage(1, 32);
  }

  // read offsets (u16): row*32 + (chunk ^ (row&3))*8, chunk = ks*2 + hi
  int aoff[2][2], boff[2][2];
#pragma unroll
  for (int i2 = 0; i2 < 2; i2++)
#pragma unroll
    for (int ks = 0; ks < 2; ks++) {
      const int ra = wr * 64 + i2 * 32 + l31;
      aoff[i2][ks] = ra * 32 + ((ks * 2 + hi) ^ (ra & 3)) * 8;
      const int rb = wc * 64 + i2 * 32 + l31;
      boff[i2][ks] = rb * 32 + ((ks * 2 + hi) ^ (rb & 3)) * 8;
    }

  int cur = 0;
  for (int kt = 0; kt < nk; ++kt) {
    if (PD == 2 && kt < nk - 1) wait_vm<G>(); else wait_vm<0>();
    __builtin_amdgcn_s_barrier();
    asm volatile("" ::: "memory");  // keep LDS reads below the barrier

    half8 a[2][2], b[2][2];
#pragma unroll
    for (int i2 = 0; i2 < 2; i2++)
#pragma unroll
      for (int ks = 0; ks < 2; ks++) {
        a[i2][ks] = *(const half8*)&smA[cur][aoff[i2][ks]];
        b[i2][ks] = *(const half8*)&smB[cur][boff[i2][ks]];
      }

    if (kt + PD < nk) {
      int pf = cur + PD; if (pf >= NBUF) pf -= NBUF;
      stage(pf, (long long)(kt + PD) * 32);
    }

#pragma unroll
    for (int ks = 0; ks < 2; ks++)
#pragma unroll
      for (int i2 = 0; i2 < 2; i2++)
#pragma unroll
        for (int j2 = 0; j2 < 2; j2++)
          acc[i2][j2] = __builtin_amdgcn_mfma_f32_32x32x16_f16(
              a[i2][ks], b[j2][ks], acc[i2][j2], 0, 0, 0);

    if constexpr (ASPLIT) {
      half8 al[2][2];
#pragma unroll
      for (int i2 = 0; i2 < 2; i2++)
#pragma unroll
        for (int ks = 0; ks < 2; ks++)
          al[i2][ks] = *(const half8*)&smA[cur][4096 + aoff[i2][ks]];
#pragma unroll
      for (int ks = 0; ks < 2; ks++)
#pragma unroll
        for (int i2 = 0; i2 < 2; i2++)
#pragma unroll
          for (int j2 = 0; j2 < 2; j2++)
            acc[i2][j2] = __builtin_amdgcn_mfma_f32_32x32x16_f16(
                al[i2][ks], b[j2][ks], acc[i2][j2], 0, 0, 0);
    }
    if constexpr (BSPLIT) {
      half8 bl[2][2];
#pragma unroll
      for (int j2 = 0; j2 < 2; j2++)
#pragma unroll
        for (int ks = 0; ks < 2; ks++)
          bl[j2][ks] = *(const half8*)&smB[cur][4096 + boff[j2][ks]];
#pragma unroll
      for (int ks = 0; ks < 2; ks++)
#pragma unroll
        for (int i2 = 0; i2 < 2; i2++)
#pragma unroll
          for (int j2 = 0; j2 < 2; j2++)
            acc[i2][j2] = __builtin_amdgcn_mfma_f32_32x32x16_f16(
                a[i2][ks], bl[j2][ks], acc[i2][j2], 0, 0, 0);
    }
    cur = (cur == NBUF - 1) ? 0 : cur + 1;
  }

  // epilogue: 32x32 C/D map: col = lane&31, row = (reg&3)+8*(reg>>2)+4*hi
#pragma unroll
  for (int i2 = 0; i2 < 2; i2++) {
#pragma unroll
    for (int j2 = 0; j2 < 2; j2++) {
      const long long gn = tN + wc * 64 + j2 * 32 + l31;
#pragma unroll
      for (int reg = 0; reg < 16; reg++) {
        const long long gm =
            tM + wr * 64 + i2 * 32 + (reg & 3) + 8 * (reg >> 2) + 4 * hi;
        float v = acc[i2][j2][reg];
        if constexpr (EPI == 1) v += (gm < biasSplit) ? bias0[gm] : bias1[gm - biasSplit];
        if constexpr (EPI == 3) v += (gn < biasSplit) ? bias0[gn] : bias1[gn - biasSplit];
        const long long off = z * sC + gm * ldc + gn;
        if constexpr (EPI == 0) {
          Cf[off] = v;
        } else if constexpr (EPI == 1) {
          u16 h = f2h(v);
          Ch[off] = h;
          Cl[off] = f2h(v - h2f(h));
        } else if constexpr (EPI == 2) {
          Cf[off] = v;
          Ch[off] = f2h(v);
        } else {
          Ch[off] = f2h(v);
        }
      }
    }
  }
  (void)biasSplit;
}

// ---------------------------------------------------------------------------
// im2col in PERMUTED k layout k' = g*512 + c  (g = ky*3+kx), reading rows of
// xt (fp16, c-contiguous) -> pure coalesced row copy, 16B/lane both sides.
// ---------------------------------------------------------------------------
__global__ void im2col_kernel(const u16* __restrict__ xt, u16* __restrict__ Ph) {
  int idx = blockIdx.x * 256 + threadIdx.x;  // < 4608*576 = 2654208
  int m = idx / 576;
  int r = idx - m * 576;
  int g = r >> 6;
  int c0 = (r & 63) * 8;
  int b = m / 576, t = m - b * 576;
  int oy = t / 24, ox = t - oy * 24;
  int ky = g / 3, kx = g - ky * 3;
  int iy = 2 * oy - 1 + ky, ix = 2 * ox - 1 + kx;
  u16x8 v = u16x8{0, 0, 0, 0, 0, 0, 0, 0};
  if (iy >= 0 && iy < 48 && ix >= 0 && ix < 48)
    v = *(const u16x8*)&xt[((long long)b * 2304 + iy * 48 + ix) * 512 + c0];
  *(u16x8*)&Ph[(long long)m * 4608 + (long long)g * 512 + c0] = v;
}

// W split2-fp16 in the SAME permuted k' = g*512 + c layout.
__global__ void wprep_kernel(const float* __restrict__ Wqc, const float* __restrict__ Wkc,
                             u16* __restrict__ Wh, u16* __restrict__ Wl) {
  int idx = blockIdx.x * 256 + threadIdx.x;  // < 1536*576 = 884736
  int n = idx / 576;
  int r = idx - n * 576;
  int g = r >> 6;
  int c0 = (r & 63) * 8;
  const float* src = (n < 1024)
      ? &Wqc[((long long)n * 512 + c0) * 9 + g]
      : &Wkc[(((long long)n - 1024) * 512 + c0) * 9 + g];
  u16x8 h8, l8;
#pragma unroll
  for (int j = 0; j < 8; j++) {
    float v = src[j * 9];
    u16 h = f2h(v);
    h8[j] = h;
    l8[j] = f2h(v - h2f(h));
  }
  long long out = (long long)n * 4608 + (long long)g * 512 + c0;
  *(u16x8*)&Wh[out] = h8;
  *(u16x8*)&Wl[out] = l8;
}

// Wqp||Wkp -> fp16 [dd][c], dd<64 qp else kp
__global__ void wp_prep(const float* __restrict__ Wqp, const float* __restrict__ Wkp,
                        u16* __restrict__ Wp) {
  int idx = blockIdx.x * 256 + threadIdx.x;  // < 128*512 = 65536
  int d = idx >> 9;
  float v = (d < 64) ? Wqp[idx] : Wkp[idx - 64 * 512];
  Wp[idx] = f2h(v);
}

// x (b,c,sp) -> xt[(b,sp)][c] fp16, tiled transpose
__global__ void xt_kernel(const float* __restrict__ x, u16* __restrict__ xt) {
  __shared__ float t[32][33];
  int b = blockIdx.z;
  int sp0 = blockIdx.x * 32, c0 = blockIdx.y * 32;
  int tx = threadIdx.x & 31, ty = threadIdx.x >> 5;  // 32 x 8
#pragma unroll
  for (int k = 0; k < 4; k++) {
    int c = c0 + ty + k * 8;
    t[ty + k * 8][tx] = x[((long long)(b * 512 + c)) * 2304 + sp0 + tx];
  }
  __syncthreads();
#pragma unroll
  for (int k = 0; k < 4; k++) {
    int sp = sp0 + ty + k * 8;
    xt[((long long)b * 2304 + sp) * 512 + c0 + tx] = f2h(t[tx][ty + k * 8]);
  }
}

// CAM softmax: attn = exp(rowmin - e)/sum  (== softmax(rowmax - e))
__global__ void softmax_cam(const float* __restrict__ E, u16* __restrict__ attn) {
  __shared__ float sm[4];
  const long long r = blockIdx.x;  // 8192 rows of 512
  const float* e = E + r * 512;
  int tid = threadIdx.x, wave = tid >> 6, lane = tid & 63;
  float v0 = e[tid], v1 = e[tid + 256];
  float mn = fminf(v0, v1);
#pragma unroll
  for (int o = 32; o; o >>= 1) mn = fminf(mn, __shfl_xor(mn, o));
  if (lane == 0) sm[wave] = mn;
  __syncthreads();
  mn = fminf(fminf(sm[0], sm[1]), fminf(sm[2], sm[3]));
  float p0 = __expf(mn - v0), p1 = __expf(mn - v1);
  float s = p0 + p1;
#pragma unroll
  for (int o = 32; o; o >>= 1) s += __shfl_xor(s, o);
  __syncthreads();
  if (lane == 0) sm[wave] = s;
  __syncthreads();
  float inv = 1.f / (sm[0] + sm[1] + sm[2] + sm[3]);
  attn[r * 512 + tid] = f2h(p0 * inv);
  attn[r * 512 + tid + 256] = f2h(p1 * inv);
}

// PAM softmax: in-place row softmax over 2304 cols (fp16), 16B/lane.
__global__ void softmax_pam(u16* __restrict__ EP) {
  __shared__ float sm[4];
  const long long r = blockIdx.x;  // 18432 rows
  u16* e = EP + r * 2304;
  int tid = threadIdx.x, wave = tid >> 6, lane = tid & 63;
  u16x8 m8 = *(const u16x8*)&e[tid * 8];
  const bool hasTail = tid < 32;
  u16x8 t8;
  if (hasTail) t8 = *(const u16x8*)&e[2048 + tid * 8];
  float v[8], w[8];
  float mx = -1e30f;
#pragma unroll
  for (int k = 0; k < 8; k++) {
    v[k] = h2f(m8[k]);
    mx = fmaxf(mx, v[k]);
  }
  if (hasTail) {
#pragma unroll
    for (int k = 0; k < 8; k++) {
      w[k] = h2f(t8[k]);
      mx = fmaxf(mx, w[k]);
    }
  }
#pragma unroll
  for (int o = 32; o; o >>= 1) mx = fmaxf(mx, __shfl_xor(mx, o));
  if (lane == 0) sm[wave] = mx;
  __syncthreads();
  mx = fmaxf(fmaxf(sm[0], sm[1]), fmaxf(sm[2], sm[3]));
  float s = 0.f;
#pragma unroll
  for (int k = 0; k < 8; k++) {
    v[k] = __expf(v[k] - mx);
    s += v[k];
  }
  if (hasTail) {
#pragma unroll
    for (int k = 0; k < 8; k++) {
      w[k] = __expf(w[k] - mx);
      s += w[k];
    }
  }
#pragma unroll
  for (int o = 32; o; o >>= 1) s += __shfl_xor(s, o);
  __syncthreads();
  if (lane == 0) sm[wave] = s;
  __syncthreads();
  float inv = 1.f / (sm[0] + sm[1] + sm[2] + sm[3]);
#pragma unroll
  for (int k = 0; k < 8; k++) m8[k] = f2h(v[k] * inv);
  *(u16x8*)&e[tid * 8] = m8;
  if (hasTail) {
#pragma unroll
    for (int k = 0; k < 8; k++) t8[k] = f2h(w[k] * inv);
    *(u16x8*)&e[2048 + tid * 8] = t8;
  }
}

// ---------------------------------------------------------------------------
extern "C" void kernel_launch(void* const* d_in, const int* in_sizes, int n_in,
                              void* d_out, int out_size, void* d_ws, size_t ws_size,
                              hipStream_t stream) {
  const float* x   = (const float*)d_in[0];
  const float* Wqc = (const float*)d_in[1];
  const float* bqc = (const float*)d_in[2];
  const float* Wkc = (const float*)d_in[3];
  const float* bkc = (const float*)d_in[4];
  const float* Wqp = (const float*)d_in[5];
  const float* bqp = (const float*)d_in[6];
  const float* Wkp = (const float*)d_in[7];
  const float* bkp = (const float*)d_in[8];
  float* outc = (float*)d_out;                 // (8,1024,2304) fp32
  float* outp = outc + 8LL * 1024 * 2304;      // (8,1024,48,48) fp32

  if (ws_size < 195166208ULL) return;  // need ~186.1 MB scratch

  char* ws = (char*)d_ws;
  // lifetime-aliased arena (fp16 buffers as u16):
  u16*   P    = (u16*)(ws + 0);             // 4608x4608       [dead after conv]
  u16*   Wh   = (u16*)(ws + 42467328LL);    // 1536x4608 hi    [dead after conv]
  u16*   Wl   = (u16*)(ws + 56623104LL);    // 1536x4608 lo    [dead after conv]
  u16*   EP   = (u16*)(ws + 0);             // 8x2304x2304     [aliases P+W]
  u16*   qcth = (u16*)(ws + 84934656LL);    // 1536x4608 hi    [dead after energy]
  u16*   qctl = (u16*)(ws + 99090432LL);    // 1536x4608 lo    [dead after energy]
  u16*   pp   = (u16*)(ws + 84934656LL);    // 18432x128       [aliases qct]
  float* E    = (float*)(ws + 113246208LL); // 8x1024x512 fp32 [dead after softmax_cam]
  u16*   attn = (u16*)(ws + 130023424LL);   // 8x1024x512      [dead after out_c]
  u16*   xt   = (u16*)(ws + 138412032LL);   // 18432x512       [dead after pp gemm]
  u16*   ocb  = (u16*)(ws + 157286400LL);   // 8x1024x2304     [till end]
  u16*   Wp   = (u16*)(ws + 195035136LL);   // 128x512

  // prep (xt must precede im2col: im2col copies from xt)
  xt_kernel<<<dim3(72, 16, 8), 256, 0, stream>>>(x, xt);
  wp_prep<<<256, 256, 0, stream>>>(Wqp, Wkp, Wp);
  wprep_kernel<<<3456, 256, 0, stream>>>(Wqc, Wkc, Wh, Wl);
  im2col_kernel<<<10368, 256, 0, stream>>>(xt, P);

  // CAM convs (W-split 2-term): qct[ch][(b,sp)] = (Wh+Wl)*P^T + bias,
  // split2-fp16 out.  L3-resident -> NBUF=2 (48KB LDS)
  gemm_bt<2, true, false, 1><<<dim3(36, 12, 1), 256, 0, stream>>>(
      Wh, Wl, P, nullptr, nullptr, qcth, qctl, bqc, bkc, 1024,
      4608, 4608, 4608, 4608, 0, 0, 0);

  // energy[b][q][c] fp32 (3-term: hh + lh + hl)
  gemm_bt<3, true, true, 0><<<dim3(4, 8, 8), 256, 0, stream>>>(
      qcth, qctl, qcth + 1024LL * 4608, qctl + 1024LL * 4608,
      E, nullptr, nullptr,
      nullptr, nullptr, 0, 576, 4608, 4608, 512, 576, 576, 524288);

  softmax_cam<<<8192, 256, 0, stream>>>(E, attn);

  // out_c[b][q][sp] = attn @ x  (fp32 -> d_out, fp16 -> ocb)
  gemm_bt<3, false, false, 2><<<dim3(18, 8, 8), 256, 0, stream>>>(
      attn, nullptr, xt, nullptr, outc, ocb, nullptr,
      nullptr, nullptr, 0, 512, 512, 512, 2304, 524288, 1179648, 2359296);

  // qp/kp 1x1 convs: pp[(b,sp)][dd] = xt @ Wp^T + bias(dd)
  gemm_bt<2, false, false, 3><<<dim3(1, 144, 1), 256, 0, stream>>>(
      xt, nullptr, Wp, nullptr, nullptr, pp, nullptr,
      bqp, bkp, 64, 512, 512, 512, 128, 0, 0, 0);

  // energy_p[b][i][j] = qp(i) . kp(j), K=64, fp16 out
  gemm_bt<3, false, false, 4><<<dim3(18, 18, 8), 256, 0, stream>>>(
      pp, nullptr, pp + 64, nullptr, nullptr, EP, nullptr,
      nullptr, nullptr, 0, 64, 128, 128, 2304, 294912, 294912, 5308416);

  softmax_pam<<<18432, 256, 0, stream>>>(EP);

  // out_p[b][q][m] = out_c @ attn_p^T (fp32 -> d_out)
  gemm_bt<3, false, false, 0><<<dim3(18, 8, 8), 256, 0, stream>>>(
      ocb, nullptr, EP, nullptr, outp, nullptr, nullptr,
      nullptr, nullptr, 0, 2304, 2304, 2304, 2304, 2359296, 5308416, 2359296);

  (void)in_sizes; (void)n_in; (void)out_size;
}

// Round 8
// 606.514 us; speedup vs baseline: 1.0630x; 1.0630x over previous
//
#include <hip/hip_runtime.h>
#include <hip/hip_bf16.h>

typedef unsigned short u16;
typedef __attribute__((ext_vector_type(8))) _Float16 half8;  // 8 fp16 in 4 VGPRs
typedef __attribute__((ext_vector_type(8))) unsigned short u16x8;
typedef __attribute__((ext_vector_type(4))) float f32x4;

static __device__ __forceinline__ u16 f2h(float v) {
  return __builtin_bit_cast(u16, (_Float16)v);
}
static __device__ __forceinline__ float h2f(u16 u) {
  return (float)__builtin_bit_cast(_Float16, u);
}

// async global->LDS, 16B per lane. LDS dest = wave-uniform base + lane*16.
static __device__ __forceinline__ void gll16(const void* g, void* l) {
  __builtin_amdgcn_global_load_lds(
      (const __attribute__((address_space(1))) unsigned int*)g,
      (__attribute__((address_space(3))) unsigned int*)l, 16, 0, 0);
}

template <int N>
static __device__ __forceinline__ void wait_vm() {
  if constexpr (N == 0) asm volatile("s_waitcnt vmcnt(0)" ::: "memory");
  else if constexpr (N == 4) asm volatile("s_waitcnt vmcnt(4)" ::: "memory");
  else if constexpr (N == 6) asm volatile("s_waitcnt vmcnt(6)" ::: "memory");
  else asm volatile("s_waitcnt vmcnt(8)" ::: "memory");
}

// ---------------------------------------------------------------------------
// gemm_bt: C[m][n] = sum_k A[m][k] * B[n][k]  (both K-contiguous, fp16).
// 128x128 tile, BK=32, 4 waves (2x2), wave tile 64x64, 16x16x32 MFMA.
// [r7 ERRATA: 32x32x16 MFMA variant tripled LDS bank conflicts (1.19e7 ->
//  3.58e7) and cost +34us on conv -- 32-row b128 read pattern is worse than
//  16-row x 4-slot. Reverted to this 16x16 form, the measured optimum.]
// NBUF=2: classic double-buffer, vmcnt(0) + barrier each K-step. Best for
//   L2/L3-resident operands (conv, pp): latency short, smaller LDS keeps
//   3 blocks/CU headroom.  [r1: conv 154.5us vs r3 3-buf 159us]
// NBUF=3: prefetch-depth 2, COUNTED vmcnt (T4): at iter kt wait vmcnt(G) so
//   stage(kt+1) stays in flight across the barrier; drain only at the end.
//   Best for HBM-latency-bound z>1 GEMMs (out_p: left top-5 since r2).
// XCD-chunked blockIdx swizzle ONLY when gridDim.z > 1 (per-batch chunking).
// For z==1 grids the natural order has better shared-L3 locality
// [r2: chunked swizzle on conv = FETCH 152->184 MB, dur +15us].
// ASPLIT: A given as hi+lo fp16; adds term Al*B.
// BSPLIT: B given as hi+lo fp16; adds term A*Bl.  (ll term dropped, ~2^-22)
// EPI: 0 = fp32 store; 1 = bias(m) + split2-fp16 store (Ch,Cl);
//      2 = fp32 + fp16 store; 3 = bias(n) + fp16 store; 4 = fp16 store
// ---------------------------------------------------------------------------
template <int NBUF, bool ASPLIT, bool BSPLIT, int EPI>
__global__ __launch_bounds__(256) void gemm_bt(
    const u16* __restrict__ A, const u16* __restrict__ Al,
    const u16* __restrict__ B, const u16* __restrict__ Bl,
    float* __restrict__ Cf, u16* __restrict__ Ch, u16* __restrict__ Cl,
    const float* __restrict__ bias0, const float* __restrict__ bias1,
    int biasSplit, int K, int lda, int ldb, int ldc,
    long long sA, long long sB, long long sC) {
  __shared__ __align__(16) u16 smA[NBUF][(ASPLIT ? 2 : 1) * 128 * 32];
  __shared__ __align__(16) u16 smB[NBUF][(BSPLIT ? 2 : 1) * 128 * 32];
  constexpr int G = 4 + (ASPLIT ? 2 : 0) + (BSPLIT ? 2 : 0);  // loads per stage
  constexpr int PD = NBUF - 1;                                 // prefetch depth

  const int tid = threadIdx.x;
  const int wave = tid >> 6, lane = tid & 63;
  const int wr = wave >> 1, wc = wave & 1;

  const int gx = gridDim.x, gy = gridDim.y;
  int bx, by;
  long long z;
  if (gridDim.z > 1) {
    const int nwg = gx * gy * (int)gridDim.z;
    const int bid = (int)blockIdx.x + gx * ((int)blockIdx.y + gy * (int)blockIdx.z);
    const int w = (bid & 7) * (nwg >> 3) + (bid >> 3);
    bx = w % gx;
    const int rem = w / gx;
    by = rem % gy;
    z = rem / gy;
  } else {
    bx = blockIdx.x;
    by = blockIdx.y;
    z = 0;
  }

  A += z * sA;
  B += z * sB;
  if (ASPLIT) Al += z * sA;
  if (BSPLIT) Bl += z * sB;
  const long long tM = (long long)by * 128;
  const long long tN = (long long)bx * 128;
  const int r4 = lane >> 2, kc = lane & 3;

  const long long arow0 = (tM + wave * 16 + r4) * (long long)lda + kc * 8;
  const long long arow1 = arow0 + 64LL * lda;
  const long long brow0 = (tN + wave * 16 + r4) * (long long)ldb + kc * 8;
  const long long brow1 = brow0 + 64LL * ldb;

  auto stage = [&](int bf, long long ko) {
    u16* dA = &smA[bf][wave * 512];
    u16* dB = &smB[bf][wave * 512];
    gll16(A + arow0 + ko, dA);
    gll16(A + arow1 + ko, dA + 2048);
    gll16(B + brow0 + ko, dB);
    gll16(B + brow1 + ko, dB + 2048);
    if constexpr (ASPLIT) {
      gll16(Al + arow0 + ko, dA + 4096);
      gll16(Al + arow1 + ko, dA + 4096 + 2048);
    }
    if constexpr (BSPLIT) {
      gll16(Bl + brow0 + ko, dB + 4096);
      gll16(Bl + brow1 + ko, dB + 4096 + 2048);
    }
  };

  f32x4 acc[4][4];
#pragma unroll
  for (int i = 0; i < 4; i++)
#pragma unroll
    for (int j = 0; j < 4; j++) acc[i][j] = f32x4{0.f, 0.f, 0.f, 0.f};

  const int quad = lane >> 4, mr = lane & 15;
  const int nk = K >> 5;

  stage(0, 0);
  if constexpr (PD == 2) {
    if (nk > 1) stage(1, 32);
  }

  int cur = 0;
  for (int kt = 0; kt < nk; ++kt) {
    if (PD == 2 && kt < nk - 1) wait_vm<G>(); else wait_vm<0>();
    __builtin_amdgcn_s_barrier();
    asm volatile("" ::: "memory");  // keep LDS reads below the barrier

    half8 a[4], b[4];
#pragma unroll
    for (int i = 0; i < 4; i++)
      a[i] = *(const half8*)&smA[cur][(wr * 64 + i * 16 + mr) * 32 + quad * 8];
#pragma unroll
    for (int j = 0; j < 4; j++)
      b[j] = *(const half8*)&smB[cur][(wc * 64 + j * 16 + mr) * 32 + quad * 8];

    if (kt + PD < nk) {
      int pf = cur + PD; if (pf >= NBUF) pf -= NBUF;
      stage(pf, (long long)(kt + PD) * 32);
    }

#pragma unroll
    for (int i = 0; i < 4; i++)
#pragma unroll
      for (int j = 0; j < 4; j++)
        acc[i][j] = __builtin_amdgcn_mfma_f32_16x16x32_f16(a[i], b[j], acc[i][j], 0, 0, 0);

    if constexpr (ASPLIT) {
      half8 al[4];
#pragma unroll
      for (int i = 0; i < 4; i++)
        al[i] = *(const half8*)&smA[cur][4096 + (wr * 64 + i * 16 + mr) * 32 + quad * 8];
#pragma unroll
      for (int i = 0; i < 4; i++)
#pragma unroll
        for (int j = 0; j < 4; j++)
          acc[i][j] = __builtin_amdgcn_mfma_f32_16x16x32_f16(al[i], b[j], acc[i][j], 0, 0, 0);
    }
    if constexpr (BSPLIT) {
      half8 bl[4];
#pragma unroll
      for (int j = 0; j < 4; j++)
        bl[j] = *(const half8*)&smB[cur][4096 + (wc * 64 + j * 16 + mr) * 32 + quad * 8];
#pragma unroll
      for (int i = 0; i < 4; i++)
#pragma unroll
        for (int j = 0; j < 4; j++)
          acc[i][j] = __builtin_amdgcn_mfma_f32_16x16x32_f16(a[i], bl[j], acc[i][j], 0, 0, 0);
    }
    cur = (cur == NBUF - 1) ? 0 : cur + 1;
  }

  // epilogue: C/D map (verified): col = lane&15, row = quad*4 + reg
#pragma unroll
  for (int i = 0; i < 4; i++) {
#pragma unroll
    for (int j = 0; j < 4; j++) {
      const long long gn = tN + wc * 64 + j * 16 + mr;
#pragma unroll
      for (int p = 0; p < 4; p++) {
        const long long gm = tM + wr * 64 + i * 16 + quad * 4 + p;
        float v = acc[i][j][p];
        if constexpr (EPI == 1) v += (gm < biasSplit) ? bias0[gm] : bias1[gm - biasSplit];
        if constexpr (EPI == 3) v += (gn < biasSplit) ? bias0[gn] : bias1[gn - biasSplit];
        const long long off = z * sC + gm * ldc + gn;
        if constexpr (EPI == 0) {
          Cf[off] = v;
        } else if constexpr (EPI == 1) {
          u16 h = f2h(v);
          Ch[off] = h;
          Cl[off] = f2h(v - h2f(h));
        } else if constexpr (EPI == 2) {
          Cf[off] = v;
          Ch[off] = f2h(v);
        } else {
          Ch[off] = f2h(v);
        }
      }
    }
  }
  (void)biasSplit;
}

// ---------------------------------------------------------------------------
// im2col in PERMUTED k layout k' = g*512 + c  (g = ky*3+kx), reading rows of
// xt (fp16, c-contiguous) -> pure coalesced row copy, 16B/lane both sides.
// ---------------------------------------------------------------------------
__global__ void im2col_kernel(const u16* __restrict__ xt, u16* __restrict__ Ph) {
  int idx = blockIdx.x * 256 + threadIdx.x;  // < 4608*576 = 2654208
  int m = idx / 576;
  int r = idx - m * 576;
  int g = r >> 6;
  int c0 = (r & 63) * 8;
  int b = m / 576, t = m - b * 576;
  int oy = t / 24, ox = t - oy * 24;
  int ky = g / 3, kx = g - ky * 3;
  int iy = 2 * oy - 1 + ky, ix = 2 * ox - 1 + kx;
  u16x8 v = u16x8{0, 0, 0, 0, 0, 0, 0, 0};
  if (iy >= 0 && iy < 48 && ix >= 0 && ix < 48)
    v = *(const u16x8*)&xt[((long long)b * 2304 + iy * 48 + ix) * 512 + c0];
  *(u16x8*)&Ph[(long long)m * 4608 + (long long)g * 512 + c0] = v;
}

// W split2-fp16 in the SAME permuted k' = g*512 + c layout; the last 256
// blocks also handle the small Wqp/Wkp -> Wp fp16 prep (fused, one launch).
__global__ void wprep_kernel(const float* __restrict__ Wqc, const float* __restrict__ Wkc,
                             u16* __restrict__ Wh, u16* __restrict__ Wl,
                             const float* __restrict__ Wqp, const float* __restrict__ Wkp,
                             u16* __restrict__ Wp) {
  if (blockIdx.x >= 3456) {
    int idx = (blockIdx.x - 3456) * 256 + threadIdx.x;  // < 128*512 = 65536
    int d = idx >> 9;
    float v = (d < 64) ? Wqp[idx] : Wkp[idx - 64 * 512];
    Wp[idx] = f2h(v);
    return;
  }
  int idx = blockIdx.x * 256 + threadIdx.x;  // < 1536*576 = 884736
  int n = idx / 576;
  int r = idx - n * 576;
  int g = r >> 6;
  int c0 = (r & 63) * 8;
  const float* src = (n < 1024)
      ? &Wqc[((long long)n * 512 + c0) * 9 + g]
      : &Wkc[(((long long)n - 1024) * 512 + c0) * 9 + g];
  u16x8 h8, l8;
#pragma unroll
  for (int j = 0; j < 8; j++) {
    float v = src[j * 9];
    u16 h = f2h(v);
    h8[j] = h;
    l8[j] = f2h(v - h2f(h));
  }
  long long out = (long long)n * 4608 + (long long)g * 512 + c0;
  *(u16x8*)&Wh[out] = h8;
  *(u16x8*)&Wl[out] = l8;
}

// x (b,c,sp) -> xt[(b,sp)][c] fp16, tiled transpose
__global__ void xt_kernel(const float* __restrict__ x, u16* __restrict__ xt) {
  __shared__ float t[32][33];
  int b = blockIdx.z;
  int sp0 = blockIdx.x * 32, c0 = blockIdx.y * 32;
  int tx = threadIdx.x & 31, ty = threadIdx.x >> 5;  // 32 x 8
#pragma unroll
  for (int k = 0; k < 4; k++) {
    int c = c0 + ty + k * 8;
    t[ty + k * 8][tx] = x[((long long)(b * 512 + c)) * 2304 + sp0 + tx];
  }
  __syncthreads();
#pragma unroll
  for (int k = 0; k < 4; k++) {
    int sp = sp0 + ty + k * 8;
    xt[((long long)b * 2304 + sp) * 512 + c0 + tx] = f2h(t[tx][ty + k * 8]);
  }
}

// CAM softmax: attn = exp(rowmin - e)/sum  (== softmax(rowmax - e))
__global__ void softmax_cam(const float* __restrict__ E, u16* __restrict__ attn) {
  __shared__ float sm[4];
  const long long r = blockIdx.x;  // 8192 rows of 512
  const float* e = E + r * 512;
  int tid = threadIdx.x, wave = tid >> 6, lane = tid & 63;
  float v0 = e[tid], v1 = e[tid + 256];
  float mn = fminf(v0, v1);
#pragma unroll
  for (int o = 32; o; o >>= 1) mn = fminf(mn, __shfl_xor(mn, o));
  if (lane == 0) sm[wave] = mn;
  __syncthreads();
  mn = fminf(fminf(sm[0], sm[1]), fminf(sm[2], sm[3]));
  float p0 = __expf(mn - v0), p1 = __expf(mn - v1);
  float s = p0 + p1;
#pragma unroll
  for (int o = 32; o; o >>= 1) s += __shfl_xor(s, o);
  __syncthreads();
  if (lane == 0) sm[wave] = s;
  __syncthreads();
  float inv = 1.f / (sm[0] + sm[1] + sm[2] + sm[3]);
  attn[r * 512 + tid] = f2h(p0 * inv);
  attn[r * 512 + tid + 256] = f2h(p1 * inv);
}

// PAM softmax: in-place row softmax over 2304 cols (fp16), 16B/lane.
// 2304 = 256 threads * 8 + 32 threads * 8 tail (threads 0-31 of wave 0).
__global__ void softmax_pam(u16* __restrict__ EP) {
  __shared__ float sm[4];
  const long long r = blockIdx.x;  // 18432 rows
  u16* e = EP + r * 2304;
  int tid = threadIdx.x, wave = tid >> 6, lane = tid & 63;
  u16x8 m8 = *(const u16x8*)&e[tid * 8];
  const bool hasTail = tid < 32;
  u16x8 t8;
  if (hasTail) t8 = *(const u16x8*)&e[2048 + tid * 8];
  float v[8], w[8];
  float mx = -1e30f;
#pragma unroll
  for (int k = 0; k < 8; k++) {
    v[k] = h2f(m8[k]);
    mx = fmaxf(mx, v[k]);
  }
  if (hasTail) {
#pragma unroll
    for (int k = 0; k < 8; k++) {
      w[k] = h2f(t8[k]);
      mx = fmaxf(mx, w[k]);
    }
  }
#pragma unroll
  for (int o = 32; o; o >>= 1) mx = fmaxf(mx, __shfl_xor(mx, o));
  if (lane == 0) sm[wave] = mx;
  __syncthreads();
  mx = fmaxf(fmaxf(sm[0], sm[1]), fmaxf(sm[2], sm[3]));
  float s = 0.f;
#pragma unroll
  for (int k = 0; k < 8; k++) {
    v[k] = __expf(v[k] - mx);
    s += v[k];
  }
  if (hasTail) {
#pragma unroll
    for (int k = 0; k < 8; k++) {
      w[k] = __expf(w[k] - mx);
      s += w[k];
    }
  }
#pragma unroll
  for (int o = 32; o; o >>= 1) s += __shfl_xor(s, o);
  __syncthreads();
  if (lane == 0) sm[wave] = s;
  __syncthreads();
  float inv = 1.f / (sm[0] + sm[1] + sm[2] + sm[3]);
#pragma unroll
  for (int k = 0; k < 8; k++) m8[k] = f2h(v[k] * inv);
  *(u16x8*)&e[tid * 8] = m8;
  if (hasTail) {
#pragma unroll
    for (int k = 0; k < 8; k++) t8[k] = f2h(w[k] * inv);
    *(u16x8*)&e[2048 + tid * 8] = t8;
  }
}

// ---------------------------------------------------------------------------
extern "C" void kernel_launch(void* const* d_in, const int* in_sizes, int n_in,
                              void* d_out, int out_size, void* d_ws, size_t ws_size,
                              hipStream_t stream) {
  const float* x   = (const float*)d_in[0];
  const float* Wqc = (const float*)d_in[1];
  const float* bqc = (const float*)d_in[2];
  const float* Wkc = (const float*)d_in[3];
  const float* bkc = (const float*)d_in[4];
  const float* Wqp = (const float*)d_in[5];
  const float* bqp = (const float*)d_in[6];
  const float* Wkp = (const float*)d_in[7];
  const float* bkp = (const float*)d_in[8];
  float* outc = (float*)d_out;                 // (8,1024,2304) fp32
  float* outp = outc + 8LL * 1024 * 2304;      // (8,1024,48,48) fp32

  if (ws_size < 195166208ULL) return;  // need ~186.1 MB scratch

  char* ws = (char*)d_ws;
  // lifetime-aliased arena (fp16 buffers as u16):
  u16*   P    = (u16*)(ws + 0);             // 4608x4608       [dead after conv]
  u16*   Wh   = (u16*)(ws + 42467328LL);    // 1536x4608 hi    [dead after conv]
  u16*   Wl   = (u16*)(ws + 56623104LL);    // 1536x4608 lo    [dead after conv]
  u16*   EP   = (u16*)(ws + 0);             // 8x2304x2304     [aliases P+W]
  u16*   qcth = (u16*)(ws + 84934656LL);    // 1536x4608 hi    [dead after energy]
  u16*   qctl = (u16*)(ws + 99090432LL);    // 1536x4608 lo    [dead after energy]
  u16*   pp   = (u16*)(ws + 84934656LL);    // 18432x128       [aliases qct]
  float* E    = (float*)(ws + 113246208LL); // 8x1024x512 fp32 [dead after softmax_cam]
  u16*   attn = (u16*)(ws + 130023424LL);   // 8x1024x512      [dead after out_c]
  u16*   xt   = (u16*)(ws + 138412032LL);   // 18432x512       [dead after pp gemm]
  u16*   ocb  = (u16*)(ws + 157286400LL);   // 8x1024x2304     [till end]
  u16*   Wp   = (u16*)(ws + 195035136LL);   // 128x512

  // prep (xt must precede im2col: im2col copies from xt)
  xt_kernel<<<dim3(72, 16, 8), 256, 0, stream>>>(x, xt);
  wprep_kernel<<<3712, 256, 0, stream>>>(Wqc, Wkc, Wh, Wl, Wqp, Wkp, Wp);
  im2col_kernel<<<10368, 256, 0, stream>>>(xt, P);

  // CAM convs (W-split 2-term): qct[ch][(b,sp)] = (Wh+Wl)*P^T + bias,
  // split2-fp16 out.  L3-resident -> NBUF=2 (48KB LDS)
  gemm_bt<2, true, false, 1><<<dim3(36, 12, 1), 256, 0, stream>>>(
      Wh, Wl, P, nullptr, nullptr, qcth, qctl, bqc, bkc, 1024,
      4608, 4608, 4608, 4608, 0, 0, 0);

  // energy[b][q][c] fp32 (3-term: hh + lh + hl)
  gemm_bt<3, true, true, 0><<<dim3(4, 8, 8), 256, 0, stream>>>(
      qcth, qctl, qcth + 1024LL * 4608, qctl + 1024LL * 4608,
      E, nullptr, nullptr,
      nullptr, nullptr, 0, 576, 4608, 4608, 512, 576, 576, 524288);

  softmax_cam<<<8192, 256, 0, stream>>>(E, attn);

  // out_c[b][q][sp] = attn @ x  (fp32 -> d_out, fp16 -> ocb)
  gemm_bt<3, false, false, 2><<<dim3(18, 8, 8), 256, 0, stream>>>(
      attn, nullptr, xt, nullptr, outc, ocb, nullptr,
      nullptr, nullptr, 0, 512, 512, 512, 2304, 524288, 1179648, 2359296);

  // qp/kp 1x1 convs: pp[(b,sp)][dd] = xt @ Wp^T + bias(dd)
  gemm_bt<2, false, false, 3><<<dim3(1, 144, 1), 256, 0, stream>>>(
      xt, nullptr, Wp, nullptr, nullptr, pp, nullptr,
      bqp, bkp, 64, 512, 512, 512, 128, 0, 0, 0);

  // energy_p[b][i][j] = qp(i) . kp(j), K=64, fp16 out
  gemm_bt<3, false, false, 4><<<dim3(18, 18, 8), 256, 0, stream>>>(
      pp, nullptr, pp + 64, nullptr, nullptr, EP, nullptr,
      nullptr, nullptr, 0, 64, 128, 128, 2304, 294912, 294912, 5308416);

  softmax_pam<<<18432, 256, 0, stream>>>(EP);

  // out_p[b][q][m] = out_c @ attn_p^T (fp32 -> d_out)
  gemm_bt<3, false, false, 0><<<dim3(18, 8, 8), 256, 0, stream>>>(
      ocb, nullptr, EP, nullptr, outp, nullptr, nullptr,
      nullptr, nullptr, 0, 2304, 2304, 2304, 2304, 2359296, 5308416, 2359296);

  (void)in_sizes; (void)n_in; (void)out_size;
}

// Round 9
// 595.831 us; speedup vs baseline: 1.0820x; 1.0179x over previous
//
#include <hip/hip_runtime.h>
#include <hip/hip_bf16.h>

typedef unsigned short u16;
typedef __attribute__((ext_vector_type(8))) _Float16 half8;  // 8 fp16 in 4 VGPRs
typedef __attribute__((ext_vector_type(8))) unsigned short u16x8;
typedef __attribute__((ext_vector_type(4))) float f32x4;

static __device__ __forceinline__ u16 f2h(float v) {
  return __builtin_bit_cast(u16, (_Float16)v);
}
static __device__ __forceinline__ float h2f(u16 u) {
  return (float)__builtin_bit_cast(_Float16, u);
}

// async global->LDS, 16B per lane. LDS dest = wave-uniform base + lane*16.
static __device__ __forceinline__ void gll16(const void* g, void* l) {
  __builtin_amdgcn_global_load_lds(
      (const __attribute__((address_space(1))) unsigned int*)g,
      (__attribute__((address_space(3))) unsigned int*)l, 16, 0, 0);
}

template <int N>
static __device__ __forceinline__ void wait_vm() {
  if constexpr (N == 0) asm volatile("s_waitcnt vmcnt(0)" ::: "memory");
  else if constexpr (N == 4) asm volatile("s_waitcnt vmcnt(4)" ::: "memory");
  else if constexpr (N == 6) asm volatile("s_waitcnt vmcnt(6)" ::: "memory");
  else asm volatile("s_waitcnt vmcnt(8)" ::: "memory");
}

// ---------------------------------------------------------------------------
// gemm_bt: C[m][n] = sum_k A[m][k] * B[n][k]  (both K-contiguous, fp16).
// 128x128 tile, BK=32, 4 waves (2x2), wave tile 64x64, 16x16x32 MFMA.
// [r7 ERRATA: 32x32x16 MFMA variant tripled LDS bank conflicts (1.19e7 ->
//  3.58e7) and cost +34us on conv. 16x16 form is the measured optimum.]
// NBUF=2: classic double-buffer, vmcnt(0) + barrier each K-step. Best for
//   L2/L3-resident operands (conv, pp).  [r1: conv 154.5us vs r3 3-buf 159us]
// NBUF=3: prefetch-depth 2, COUNTED vmcnt (T4): at iter kt wait vmcnt(G) so
//   stage(kt+1) stays in flight across the barrier; drain only at the end.
//   Best for HBM-latency-bound z>1 GEMMs (out_p: left top-5 since r2).
// XCD-chunked blockIdx swizzle ONLY when gridDim.z > 1 (per-batch chunking).
// [r2: chunked swizzle on z==1 conv = FETCH 152->184 MB, dur +15us].
// ASPLIT: A given as hi+lo fp16; adds term Al*B.
// BSPLIT: B given as hi+lo fp16; adds term A*Bl.  (ll term dropped, ~2^-22)
// EPI: 0 = fp32 store; 1 = bias(m) + split2-fp16 store (Ch,Cl);
//      2 = fp32 + fp16 store; 3 = bias(n) + fp16 store; 4 = fp16 store;
//      5 = fp16 store of exp(v-4)   [unnormalized PAM attn numerator];
//      6 = fp32 store of v * bias0[z*biasSplit + gn]  [denominator factored
//          out of the PV GEMM -- flash-attention identity]
// ---------------------------------------------------------------------------
template <int NBUF, bool ASPLIT, bool BSPLIT, int EPI>
__global__ __launch_bounds__(256) void gemm_bt(
    const u16* __restrict__ A, const u16* __restrict__ Al,
    const u16* __restrict__ B, const u16* __restrict__ Bl,
    float* __restrict__ Cf, u16* __restrict__ Ch, u16* __restrict__ Cl,
    const float* __restrict__ bias0, const float* __restrict__ bias1,
    int biasSplit, int K, int lda, int ldb, int ldc,
    long long sA, long long sB, long long sC) {
  __shared__ __align__(16) u16 smA[NBUF][(ASPLIT ? 2 : 1) * 128 * 32];
  __shared__ __align__(16) u16 smB[NBUF][(BSPLIT ? 2 : 1) * 128 * 32];
  constexpr int G = 4 + (ASPLIT ? 2 : 0) + (BSPLIT ? 2 : 0);  // loads per stage
  constexpr int PD = NBUF - 1;                                 // prefetch depth

  const int tid = threadIdx.x;
  const int wave = tid >> 6, lane = tid & 63;
  const int wr = wave >> 1, wc = wave & 1;

  const int gx = gridDim.x, gy = gridDim.y;
  int bx, by;
  long long z;
  if (gridDim.z > 1) {
    const int nwg = gx * gy * (int)gridDim.z;
    const int bid = (int)blockIdx.x + gx * ((int)blockIdx.y + gy * (int)blockIdx.z);
    const int w = (bid & 7) * (nwg >> 3) + (bid >> 3);
    bx = w % gx;
    const int rem = w / gx;
    by = rem % gy;
    z = rem / gy;
  } else {
    bx = blockIdx.x;
    by = blockIdx.y;
    z = 0;
  }

  A += z * sA;
  B += z * sB;
  if (ASPLIT) Al += z * sA;
  if (BSPLIT) Bl += z * sB;
  const long long tM = (long long)by * 128;
  const long long tN = (long long)bx * 128;
  const int r4 = lane >> 2, kc = lane & 3;

  const long long arow0 = (tM + wave * 16 + r4) * (long long)lda + kc * 8;
  const long long arow1 = arow0 + 64LL * lda;
  const long long brow0 = (tN + wave * 16 + r4) * (long long)ldb + kc * 8;
  const long long brow1 = brow0 + 64LL * ldb;

  auto stage = [&](int bf, long long ko) {
    u16* dA = &smA[bf][wave * 512];
    u16* dB = &smB[bf][wave * 512];
    gll16(A + arow0 + ko, dA);
    gll16(A + arow1 + ko, dA + 2048);
    gll16(B + brow0 + ko, dB);
    gll16(B + brow1 + ko, dB + 2048);
    if constexpr (ASPLIT) {
      gll16(Al + arow0 + ko, dA + 4096);
      gll16(Al + arow1 + ko, dA + 4096 + 2048);
    }
    if constexpr (BSPLIT) {
      gll16(Bl + brow0 + ko, dB + 4096);
      gll16(Bl + brow1 + ko, dB + 4096 + 2048);
    }
  };

  f32x4 acc[4][4];
#pragma unroll
  for (int i = 0; i < 4; i++)
#pragma unroll
    for (int j = 0; j < 4; j++) acc[i][j] = f32x4{0.f, 0.f, 0.f, 0.f};

  const int quad = lane >> 4, mr = lane & 15;
  const int nk = K >> 5;

  stage(0, 0);
  if constexpr (PD == 2) {
    if (nk > 1) stage(1, 32);
  }

  int cur = 0;
  for (int kt = 0; kt < nk; ++kt) {
    if (PD == 2 && kt < nk - 1) wait_vm<G>(); else wait_vm<0>();
    __builtin_amdgcn_s_barrier();
    asm volatile("" ::: "memory");  // keep LDS reads below the barrier

    half8 a[4], b[4];
#pragma unroll
    for (int i = 0; i < 4; i++)
      a[i] = *(const half8*)&smA[cur][(wr * 64 + i * 16 + mr) * 32 + quad * 8];
#pragma unroll
    for (int j = 0; j < 4; j++)
      b[j] = *(const half8*)&smB[cur][(wc * 64 + j * 16 + mr) * 32 + quad * 8];

    if (kt + PD < nk) {
      int pf = cur + PD; if (pf >= NBUF) pf -= NBUF;
      stage(pf, (long long)(kt + PD) * 32);
    }

#pragma unroll
    for (int i = 0; i < 4; i++)
#pragma unroll
      for (int j = 0; j < 4; j++)
        acc[i][j] = __builtin_amdgcn_mfma_f32_16x16x32_f16(a[i], b[j], acc[i][j], 0, 0, 0);

    if constexpr (ASPLIT) {
      half8 al[4];
#pragma unroll
      for (int i = 0; i < 4; i++)
        al[i] = *(const half8*)&smA[cur][4096 + (wr * 64 + i * 16 + mr) * 32 + quad * 8];
#pragma unroll
      for (int i = 0; i < 4; i++)
#pragma unroll
        for (int j = 0; j < 4; j++)
          acc[i][j] = __builtin_amdgcn_mfma_f32_16x16x32_f16(al[i], b[j], acc[i][j], 0, 0, 0);
    }
    if constexpr (BSPLIT) {
      half8 bl[4];
#pragma unroll
      for (int j = 0; j < 4; j++)
        bl[j] = *(const half8*)&smB[cur][4096 + (wc * 64 + j * 16 + mr) * 32 + quad * 8];
#pragma unroll
      for (int i = 0; i < 4; i++)
#pragma unroll
        for (int j = 0; j < 4; j++)
          acc[i][j] = __builtin_amdgcn_mfma_f32_16x16x32_f16(a[i], bl[j], acc[i][j], 0, 0, 0);
    }
    cur = (cur == NBUF - 1) ? 0 : cur + 1;
  }

  // epilogue: C/D map (verified): col = lane&15, row = quad*4 + reg
#pragma unroll
  for (int i = 0; i < 4; i++) {
#pragma unroll
    for (int j = 0; j < 4; j++) {
      const long long gn = tN + wc * 64 + j * 16 + mr;
#pragma unroll
      for (int p = 0; p < 4; p++) {
        const long long gm = tM + wr * 64 + i * 16 + quad * 4 + p;
        float v = acc[i][j][p];
        if constexpr (EPI == 1) v += (gm < biasSplit) ? bias0[gm] : bias1[gm - biasSplit];
        if constexpr (EPI == 3) v += (gn < biasSplit) ? bias0[gn] : bias1[gn - biasSplit];
        if constexpr (EPI == 6) v *= bias0[z * biasSplit + gn];
        const long long off = z * sC + gm * ldc + gn;
        if constexpr (EPI == 0 || EPI == 6) {
          Cf[off] = v;
        } else if constexpr (EPI == 1) {
          u16 h = f2h(v);
          Ch[off] = h;
          Cl[off] = f2h(v - h2f(h));
        } else if constexpr (EPI == 2) {
          Cf[off] = v;
          Ch[off] = f2h(v);
        } else if constexpr (EPI == 5) {
          Ch[off] = f2h(__expf(v - 4.0f));
        } else {
          Ch[off] = f2h(v);
        }
      }
    }
  }
  (void)biasSplit;
}

// ---------------------------------------------------------------------------
// im2col in PERMUTED k layout k' = g*512 + c  (g = ky*3+kx), reading rows of
// xt (fp16, c-contiguous) -> pure coalesced row copy, 16B/lane both sides.
// ---------------------------------------------------------------------------
__global__ void im2col_kernel(const u16* __restrict__ xt, u16* __restrict__ Ph) {
  int idx = blockIdx.x * 256 + threadIdx.x;  // < 4608*576 = 2654208
  int m = idx / 576;
  int r = idx - m * 576;
  int g = r >> 6;
  int c0 = (r & 63) * 8;
  int b = m / 576, t = m - b * 576;
  int oy = t / 24, ox = t - oy * 24;
  int ky = g / 3, kx = g - ky * 3;
  int iy = 2 * oy - 1 + ky, ix = 2 * ox - 1 + kx;
  u16x8 v = u16x8{0, 0, 0, 0, 0, 0, 0, 0};
  if (iy >= 0 && iy < 48 && ix >= 0 && ix < 48)
    v = *(const u16x8*)&xt[((long long)b * 2304 + iy * 48 + ix) * 512 + c0];
  *(u16x8*)&Ph[(long long)m * 4608 + (long long)g * 512 + c0] = v;
}

// W split2-fp16 in the SAME permuted k' = g*512 + c layout; the last 256
// blocks also handle the small Wqp/Wkp -> Wp fp16 prep (fused, one launch).
__global__ void wprep_kernel(const float* __restrict__ Wqc, const float* __restrict__ Wkc,
                             u16* __restrict__ Wh, u16* __restrict__ Wl,
                             const float* __restrict__ Wqp, const float* __restrict__ Wkp,
                             u16* __restrict__ Wp) {
  if (blockIdx.x >= 3456) {
    int idx = (blockIdx.x - 3456) * 256 + threadIdx.x;  // < 128*512 = 65536
    int d = idx >> 9;
    float v = (d < 64) ? Wqp[idx] : Wkp[idx - 64 * 512];
    Wp[idx] = f2h(v);
    return;
  }
  int idx = blockIdx.x * 256 + threadIdx.x;  // < 1536*576 = 884736
  int n = idx / 576;
  int r = idx - n * 576;
  int g = r >> 6;
  int c0 = (r & 63) * 8;
  const float* src = (n < 1024)
      ? &Wqc[((long long)n * 512 + c0) * 9 + g]
      : &Wkc[(((long long)n - 1024) * 512 + c0) * 9 + g];
  u16x8 h8, l8;
#pragma unroll
  for (int j = 0; j < 8; j++) {
    float v = src[j * 9];
    u16 h = f2h(v);
    h8[j] = h;
    l8[j] = f2h(v - h2f(h));
  }
  long long out = (long long)n * 4608 + (long long)g * 512 + c0;
  *(u16x8*)&Wh[out] = h8;
  *(u16x8*)&Wl[out] = l8;
}

// x (b,c,sp) -> xt[(b,sp)][c] fp16, tiled transpose
__global__ void xt_kernel(const float* __restrict__ x, u16* __restrict__ xt) {
  __shared__ float t[32][33];
  int b = blockIdx.z;
  int sp0 = blockIdx.x * 32, c0 = blockIdx.y * 32;
  int tx = threadIdx.x & 31, ty = threadIdx.x >> 5;  // 32 x 8
#pragma unroll
  for (int k = 0; k < 4; k++) {
    int c = c0 + ty + k * 8;
    t[ty + k * 8][tx] = x[((long long)(b * 512 + c)) * 2304 + sp0 + tx];
  }
  __syncthreads();
#pragma unroll
  for (int k = 0; k < 4; k++) {
    int sp = sp0 + ty + k * 8;
    xt[((long long)b * 2304 + sp) * 512 + c0 + tx] = f2h(t[tx][ty + k * 8]);
  }
}

// CAM softmax: attn = exp(rowmin - e)/sum  (== softmax(rowmax - e))
__global__ void softmax_cam(const float* __restrict__ E, u16* __restrict__ attn) {
  __shared__ float sm[4];
  const long long r = blockIdx.x;  // 8192 rows of 512
  const float* e = E + r * 512;
  int tid = threadIdx.x, wave = tid >> 6, lane = tid & 63;
  float v0 = e[tid], v1 = e[tid + 256];
  float mn = fminf(v0, v1);
#pragma unroll
  for (int o = 32; o; o >>= 1) mn = fminf(mn, __shfl_xor(mn, o));
  if (lane == 0) sm[wave] = mn;
  __syncthreads();
  mn = fminf(fminf(sm[0], sm[1]), fminf(sm[2], sm[3]));
  float p0 = __expf(mn - v0), p1 = __expf(mn - v1);
  float s = p0 + p1;
#pragma unroll
  for (int o = 32; o; o >>= 1) s += __shfl_xor(s, o);
  __syncthreads();
  if (lane == 0) sm[wave] = s;
  __syncthreads();
  float inv = 1.f / (sm[0] + sm[1] + sm[2] + sm[3]);
  attn[r * 512 + tid] = f2h(p0 * inv);
  attn[r * 512 + tid + 256] = f2h(p1 * inv);
}

// PAM row-sum: EP holds exp(e-4) fp16 (written by energy_p EPI=5).
// inv[r] = 1 / sum_n EP[r][n].  The softmax denominator -- applied in
// out_p's epilogue (EPI=6), so no normalization pass over EP is needed.
__global__ void rowsum_inv(const u16* __restrict__ EP, float* __restrict__ inv) {
  __shared__ float sm[4];
  const long long r = blockIdx.x;  // 18432 rows
  const u16* e = EP + r * 2304;
  int tid = threadIdx.x, wave = tid >> 6, lane = tid & 63;
  u16x8 m8 = *(const u16x8*)&e[tid * 8];
  float s = 0.f;
#pragma unroll
  for (int k = 0; k < 8; k++) s += h2f(m8[k]);
  if (tid < 32) {
    u16x8 t8 = *(const u16x8*)&e[2048 + tid * 8];
#pragma unroll
    for (int k = 0; k < 8; k++) s += h2f(t8[k]);
  }
#pragma unroll
  for (int o = 32; o; o >>= 1) s += __shfl_xor(s, o);
  if (lane == 0) sm[wave] = s;
  __syncthreads();
  if (tid == 0) inv[r] = 1.f / (sm[0] + sm[1] + sm[2] + sm[3]);
}

// ---------------------------------------------------------------------------
extern "C" void kernel_launch(void* const* d_in, const int* in_sizes, int n_in,
                              void* d_out, int out_size, void* d_ws, size_t ws_size,
                              hipStream_t stream) {
  const float* x   = (const float*)d_in[0];
  const float* Wqc = (const float*)d_in[1];
  const float* bqc = (const float*)d_in[2];
  const float* Wkc = (const float*)d_in[3];
  const float* bkc = (const float*)d_in[4];
  const float* Wqp = (const float*)d_in[5];
  const float* bqp = (const float*)d_in[6];
  const float* Wkp = (const float*)d_in[7];
  const float* bkp = (const float*)d_in[8];
  float* outc = (float*)d_out;                 // (8,1024,2304) fp32
  float* outp = outc + 8LL * 1024 * 2304;      // (8,1024,48,48) fp32

  if (ws_size < 195166208ULL) return;  // need ~186.1 MB scratch

  char* ws = (char*)d_ws;
  // lifetime-aliased arena (fp16 buffers as u16):
  u16*   P    = (u16*)(ws + 0);             // 4608x4608       [dead after conv]
  u16*   Wh   = (u16*)(ws + 42467328LL);    // 1536x4608 hi    [dead after conv]
  u16*   Wl   = (u16*)(ws + 56623104LL);    // 1536x4608 lo    [dead after conv]
  u16*   EP   = (u16*)(ws + 0);             // 8x2304x2304     [aliases P+W]
  u16*   qcth = (u16*)(ws + 84934656LL);    // 1536x4608 hi    [dead after energy]
  u16*   qctl = (u16*)(ws + 99090432LL);    // 1536x4608 lo    [dead after energy]
  u16*   pp   = (u16*)(ws + 84934656LL);    // 18432x128       [aliases qct]
  float* E    = (float*)(ws + 113246208LL); // 8x1024x512 fp32 [dead after softmax_cam]
  float* inv  = (float*)(ws + 113246208LL); // 18432 fp32      [aliases dead E]
  u16*   attn = (u16*)(ws + 130023424LL);   // 8x1024x512      [dead after out_c]
  u16*   xt   = (u16*)(ws + 138412032LL);   // 18432x512       [dead after pp gemm]
  u16*   ocb  = (u16*)(ws + 157286400LL);   // 8x1024x2304     [till end]
  u16*   Wp   = (u16*)(ws + 195035136LL);   // 128x512

  // prep (xt must precede im2col: im2col copies from xt)
  xt_kernel<<<dim3(72, 16, 8), 256, 0, stream>>>(x, xt);
  wprep_kernel<<<3712, 256, 0, stream>>>(Wqc, Wkc, Wh, Wl, Wqp, Wkp, Wp);
  im2col_kernel<<<10368, 256, 0, stream>>>(xt, P);

  // CAM convs (W-split 2-term): qct[ch][(b,sp)] = (Wh+Wl)*P^T + bias,
  // split2-fp16 out.  L3-resident -> NBUF=2 (48KB LDS)
  gemm_bt<2, true, false, 1><<<dim3(36, 12, 1), 256, 0, stream>>>(
      Wh, Wl, P, nullptr, nullptr, qcth, qctl, bqc, bkc, 1024,
      4608, 4608, 4608, 4608, 0, 0, 0);

  // energy[b][q][c] fp32 (3-term: hh + lh + hl)
  gemm_bt<3, true, true, 0><<<dim3(4, 8, 8), 256, 0, stream>>>(
      qcth, qctl, qcth + 1024LL * 4608, qctl + 1024LL * 4608,
      E, nullptr, nullptr,
      nullptr, nullptr, 0, 576, 4608, 4608, 512, 576, 576, 524288);

  softmax_cam<<<8192, 256, 0, stream>>>(E, attn);

  // out_c[b][q][sp] = attn @ x  (fp32 -> d_out, fp16 -> ocb)
  gemm_bt<3, false, false, 2><<<dim3(18, 8, 8), 256, 0, stream>>>(
      attn, nullptr, xt, nullptr, outc, ocb, nullptr,
      nullptr, nullptr, 0, 512, 512, 512, 2304, 524288, 1179648, 2359296);

  // qp/kp 1x1 convs: pp[(b,sp)][dd] = xt @ Wp^T + bias(dd)
  gemm_bt<2, false, false, 3><<<dim3(1, 144, 1), 256, 0, stream>>>(
      xt, nullptr, Wp, nullptr, nullptr, pp, nullptr,
      bqp, bkp, 64, 512, 512, 512, 128, 0, 0, 0);

  // energy_p[b][i][j] = qp(i).kp(j), K=64 -> stores exp(e-4) fp16 (EPI=5)
  gemm_bt<3, false, false, 5><<<dim3(18, 18, 8), 256, 0, stream>>>(
      pp, nullptr, pp + 64, nullptr, nullptr, EP, nullptr,
      nullptr, nullptr, 0, 64, 128, 128, 2304, 294912, 294912, 5308416);

  // softmax denominators (replaces full softmax_pam pass: -170MB traffic)
  rowsum_inv<<<18432, 256, 0, stream>>>(EP, inv);

  // out_p[b][q][m] = (ocb @ expEP^T) * inv[m]  (EPI=6 column scale)
  gemm_bt<3, false, false, 6><<<dim3(18, 8, 8), 256, 0, stream>>>(
      ocb, nullptr, EP, nullptr, outp, nullptr, nullptr,
      inv, nullptr, 2304, 2304, 2304, 2304, 2304, 2359296, 5308416, 2359296);

  (void)in_sizes; (void)n_in; (void)out_size;
}

// Round 10
// 560.161 us; speedup vs baseline: 1.1509x; 1.0637x over previous
//
#include <hip/hip_runtime.h>
#include <hip/hip_bf16.h>

typedef unsigned short u16;
typedef __attribute__((ext_vector_type(8))) _Float16 half8;  // 8 fp16 in 4 VGPRs
typedef __attribute__((ext_vector_type(8))) unsigned short u16x8;
typedef __attribute__((ext_vector_type(4))) float f32x4;

static __device__ __forceinline__ u16 f2h(float v) {
  return __builtin_bit_cast(u16, (_Float16)v);
}
static __device__ __forceinline__ float h2f(u16 u) {
  return (float)__builtin_bit_cast(_Float16, u);
}

// async global->LDS, 16B per lane. LDS dest = wave-uniform base + lane*16.
static __device__ __forceinline__ void gll16(const void* g, void* l) {
  __builtin_amdgcn_global_load_lds(
      (const __attribute__((address_space(1))) unsigned int*)g,
      (__attribute__((address_space(3))) unsigned int*)l, 16, 0, 0);
}

template <int N>
static __device__ __forceinline__ void wait_vm() {
  if constexpr (N == 0) asm volatile("s_waitcnt vmcnt(0)" ::: "memory");
  else if constexpr (N == 4) asm volatile("s_waitcnt vmcnt(4)" ::: "memory");
  else if constexpr (N == 6) asm volatile("s_waitcnt vmcnt(6)" ::: "memory");
  else asm volatile("s_waitcnt vmcnt(8)" ::: "memory");
}

// ---------------------------------------------------------------------------
// gemm_bt: C[m][n] = sum_k A[m][k] * B[n][k]  (both K-contiguous, fp16).
// 128x128 tile, BK=32, 4 waves (2x2), wave tile 64x64, 16x16x32 MFMA.
// [r7 ERRATA: 32x32x16 MFMA variant tripled LDS bank conflicts (1.19e7 ->
//  3.58e7) and cost +34us on conv. 16x16 form is the measured optimum.]
// NBUF=2: classic double-buffer, vmcnt(0) + barrier each K-step. Best for
//   L2/L3-resident operands (conv, pp).  [r1: conv 154.5us vs r3 3-buf 159us]
// NBUF=3: prefetch-depth 2, COUNTED vmcnt (T4): at iter kt wait vmcnt(G) so
//   stage(kt+1) stays in flight across the barrier; drain only at the end.
//   Best for HBM-latency-bound z>1 GEMMs (out_p: left top-5 since r2).
// XCD-chunked blockIdx swizzle ONLY when gridDim.z > 1 (per-batch chunking).
// [r2: chunked swizzle on z==1 conv = FETCH 152->184 MB, dur +15us].
// ASPLIT: A given as hi+lo fp16; adds term Al*B.
// BSPLIT: B given as hi+lo fp16; adds term A*Bl.  (ll term dropped, ~2^-22)
// EPI: 0 = fp32 store; 1 = bias(m) + split2-fp16 store (Ch,Cl);
//      2 = fp32 + fp16 store; 3 = bias(n) + fp16 store; 4 = fp16 store;
//      5 = fp16 store of exp(v-4)   [unnormalized PAM attn numerator];
//      6 = fp32 store of v * bias0[z*biasSplit + gn]  [denominator factored
//          out of the PV GEMM -- flash-attention identity]
// ---------------------------------------------------------------------------
template <int NBUF, bool ASPLIT, bool BSPLIT, int EPI>
__global__ __launch_bounds__(256) void gemm_bt(
    const u16* __restrict__ A, const u16* __restrict__ Al,
    const u16* __restrict__ B, const u16* __restrict__ Bl,
    float* __restrict__ Cf, u16* __restrict__ Ch, u16* __restrict__ Cl,
    const float* __restrict__ bias0, const float* __restrict__ bias1,
    int biasSplit, int K, int lda, int ldb, int ldc,
    long long sA, long long sB, long long sC) {
  __shared__ __align__(16) u16 smA[NBUF][(ASPLIT ? 2 : 1) * 128 * 32];
  __shared__ __align__(16) u16 smB[NBUF][(BSPLIT ? 2 : 1) * 128 * 32];
  constexpr int G = 4 + (ASPLIT ? 2 : 0) + (BSPLIT ? 2 : 0);  // loads per stage
  constexpr int PD = NBUF - 1;                                 // prefetch depth

  const int tid = threadIdx.x;
  const int wave = tid >> 6, lane = tid & 63;
  const int wr = wave >> 1, wc = wave & 1;

  const int gx = gridDim.x, gy = gridDim.y;
  int bx, by;
  long long z;
  if (gridDim.z > 1) {
    const int nwg = gx * gy * (int)gridDim.z;
    const int bid = (int)blockIdx.x + gx * ((int)blockIdx.y + gy * (int)blockIdx.z);
    const int w = (bid & 7) * (nwg >> 3) + (bid >> 3);
    bx = w % gx;
    const int rem = w / gx;
    by = rem % gy;
    z = rem / gy;
  } else {
    bx = blockIdx.x;
    by = blockIdx.y;
    z = 0;
  }

  A += z * sA;
  B += z * sB;
  if (ASPLIT) Al += z * sA;
  if (BSPLIT) Bl += z * sB;
  const long long tM = (long long)by * 128;
  const long long tN = (long long)bx * 128;
  const int r4 = lane >> 2, kc = lane & 3;

  const long long arow0 = (tM + wave * 16 + r4) * (long long)lda + kc * 8;
  const long long arow1 = arow0 + 64LL * lda;
  const long long brow0 = (tN + wave * 16 + r4) * (long long)ldb + kc * 8;
  const long long brow1 = brow0 + 64LL * ldb;

  auto stage = [&](int bf, long long ko) {
    u16* dA = &smA[bf][wave * 512];
    u16* dB = &smB[bf][wave * 512];
    gll16(A + arow0 + ko, dA);
    gll16(A + arow1 + ko, dA + 2048);
    gll16(B + brow0 + ko, dB);
    gll16(B + brow1 + ko, dB + 2048);
    if constexpr (ASPLIT) {
      gll16(Al + arow0 + ko, dA + 4096);
      gll16(Al + arow1 + ko, dA + 4096 + 2048);
    }
    if constexpr (BSPLIT) {
      gll16(Bl + brow0 + ko, dB + 4096);
      gll16(Bl + brow1 + ko, dB + 4096 + 2048);
    }
  };

  f32x4 acc[4][4];
#pragma unroll
  for (int i = 0; i < 4; i++)
#pragma unroll
    for (int j = 0; j < 4; j++) acc[i][j] = f32x4{0.f, 0.f, 0.f, 0.f};

  const int quad = lane >> 4, mr = lane & 15;
  const int nk = K >> 5;

  stage(0, 0);
  if constexpr (PD == 2) {
    if (nk > 1) stage(1, 32);
  }

  int cur = 0;
  for (int kt = 0; kt < nk; ++kt) {
    if (PD == 2 && kt < nk - 1) wait_vm<G>(); else wait_vm<0>();
    __builtin_amdgcn_s_barrier();
    asm volatile("" ::: "memory");  // keep LDS reads below the barrier

    half8 a[4], b[4];
#pragma unroll
    for (int i = 0; i < 4; i++)
      a[i] = *(const half8*)&smA[cur][(wr * 64 + i * 16 + mr) * 32 + quad * 8];
#pragma unroll
    for (int j = 0; j < 4; j++)
      b[j] = *(const half8*)&smB[cur][(wc * 64 + j * 16 + mr) * 32 + quad * 8];

    if (kt + PD < nk) {
      int pf = cur + PD; if (pf >= NBUF) pf -= NBUF;
      stage(pf, (long long)(kt + PD) * 32);
    }

#pragma unroll
    for (int i = 0; i < 4; i++)
#pragma unroll
      for (int j = 0; j < 4; j++)
        acc[i][j] = __builtin_amdgcn_mfma_f32_16x16x32_f16(a[i], b[j], acc[i][j], 0, 0, 0);

    if constexpr (ASPLIT) {
      half8 al[4];
#pragma unroll
      for (int i = 0; i < 4; i++)
        al[i] = *(const half8*)&smA[cur][4096 + (wr * 64 + i * 16 + mr) * 32 + quad * 8];
#pragma unroll
      for (int i = 0; i < 4; i++)
#pragma unroll
        for (int j = 0; j < 4; j++)
          acc[i][j] = __builtin_amdgcn_mfma_f32_16x16x32_f16(al[i], b[j], acc[i][j], 0, 0, 0);
    }
    if constexpr (BSPLIT) {
      half8 bl[4];
#pragma unroll
      for (int j = 0; j < 4; j++)
        bl[j] = *(const half8*)&smB[cur][4096 + (wc * 64 + j * 16 + mr) * 32 + quad * 8];
#pragma unroll
      for (int i = 0; i < 4; i++)
#pragma unroll
        for (int j = 0; j < 4; j++)
          acc[i][j] = __builtin_amdgcn_mfma_f32_16x16x32_f16(a[i], bl[j], acc[i][j], 0, 0, 0);
    }
    cur = (cur == NBUF - 1) ? 0 : cur + 1;
  }

  // epilogue: C/D map (verified): col = lane&15, row = quad*4 + reg
#pragma unroll
  for (int i = 0; i < 4; i++) {
#pragma unroll
    for (int j = 0; j < 4; j++) {
      const long long gn = tN + wc * 64 + j * 16 + mr;
#pragma unroll
      for (int p = 0; p < 4; p++) {
        const long long gm = tM + wr * 64 + i * 16 + quad * 4 + p;
        float v = acc[i][j][p];
        if constexpr (EPI == 1) v += (gm < biasSplit) ? bias0[gm] : bias1[gm - biasSplit];
        if constexpr (EPI == 3) v += (gn < biasSplit) ? bias0[gn] : bias1[gn - biasSplit];
        if constexpr (EPI == 6) v *= bias0[z * biasSplit + gn];
        const long long off = z * sC + gm * ldc + gn;
        if constexpr (EPI == 0 || EPI == 6) {
          Cf[off] = v;
        } else if constexpr (EPI == 1) {
          u16 h = f2h(v);
          Ch[off] = h;
          Cl[off] = f2h(v - h2f(h));
        } else if constexpr (EPI == 2) {
          Cf[off] = v;
          Ch[off] = f2h(v);
        } else if constexpr (EPI == 5) {
          Ch[off] = f2h(__expf(v - 4.0f));
        } else {
          Ch[off] = f2h(v);
        }
      }
    }
  }
  (void)biasSplit;
}

// ---------------------------------------------------------------------------
// im2col in PERMUTED k layout k' = g*512 + c  (g = ky*3+kx), reading rows of
// xt (fp16, c-contiguous) -> pure coalesced row copy, 16B/lane both sides.
// ---------------------------------------------------------------------------
__global__ void im2col_kernel(const u16* __restrict__ xt, u16* __restrict__ Ph) {
  int idx = blockIdx.x * 256 + threadIdx.x;  // < 4608*576 = 2654208
  int m = idx / 576;
  int r = idx - m * 576;
  int g = r >> 6;
  int c0 = (r & 63) * 8;
  int b = m / 576, t = m - b * 576;
  int oy = t / 24, ox = t - oy * 24;
  int ky = g / 3, kx = g - ky * 3;
  int iy = 2 * oy - 1 + ky, ix = 2 * ox - 1 + kx;
  u16x8 v = u16x8{0, 0, 0, 0, 0, 0, 0, 0};
  if (iy >= 0 && iy < 48 && ix >= 0 && ix < 48)
    v = *(const u16x8*)&xt[((long long)b * 2304 + iy * 48 + ix) * 512 + c0];
  *(u16x8*)&Ph[(long long)m * 4608 + (long long)g * 512 + c0] = v;
}

// W split2-fp16 in the SAME permuted k' = g*512 + c layout; the last 256
// blocks also handle the small Wqp/Wkp -> Wp fp16 prep (fused, one launch).
__global__ void wprep_kernel(const float* __restrict__ Wqc, const float* __restrict__ Wkc,
                             u16* __restrict__ Wh, u16* __restrict__ Wl,
                             const float* __restrict__ Wqp, const float* __restrict__ Wkp,
                             u16* __restrict__ Wp) {
  if (blockIdx.x >= 3456) {
    int idx = (blockIdx.x - 3456) * 256 + threadIdx.x;  // < 128*512 = 65536
    int d = idx >> 9;
    float v = (d < 64) ? Wqp[idx] : Wkp[idx - 64 * 512];
    Wp[idx] = f2h(v);
    return;
  }
  int idx = blockIdx.x * 256 + threadIdx.x;  // < 1536*576 = 884736
  int n = idx / 576;
  int r = idx - n * 576;
  int g = r >> 6;
  int c0 = (r & 63) * 8;
  const float* src = (n < 1024)
      ? &Wqc[((long long)n * 512 + c0) * 9 + g]
      : &Wkc[(((long long)n - 1024) * 512 + c0) * 9 + g];
  u16x8 h8, l8;
#pragma unroll
  for (int j = 0; j < 8; j++) {
    float v = src[j * 9];
    u16 h = f2h(v);
    h8[j] = h;
    l8[j] = f2h(v - h2f(h));
  }
  long long out = (long long)n * 4608 + (long long)g * 512 + c0;
  *(u16x8*)&Wh[out] = h8;
  *(u16x8*)&Wl[out] = l8;
}

// x (b,c,sp) -> xt[(b,sp)][c] fp16 (tiled transpose) AND xh[(b,c)][sp] fp16
// (straight cast, coalesced along sp -- feeds the reassociated PAM-PV GEMM).
__global__ void xt_kernel(const float* __restrict__ x, u16* __restrict__ xt,
                          u16* __restrict__ xh) {
  __shared__ float t[32][33];
  int b = blockIdx.z;
  int sp0 = blockIdx.x * 32, c0 = blockIdx.y * 32;
  int tx = threadIdx.x & 31, ty = threadIdx.x >> 5;  // 32 x 8
#pragma unroll
  for (int k = 0; k < 4; k++) {
    int c = c0 + ty + k * 8;
    long long src = ((long long)(b * 512 + c)) * 2304 + sp0 + tx;
    float v = x[src];
    t[ty + k * 8][tx] = v;
    xh[src] = f2h(v);
  }
  __syncthreads();
#pragma unroll
  for (int k = 0; k < 4; k++) {
    int sp = sp0 + ty + k * 8;
    xt[((long long)b * 2304 + sp) * 512 + c0 + tx] = f2h(t[tx][ty + k * 8]);
  }
}

// CAM softmax: attn = exp(rowmin - e)/sum  (== softmax(rowmax - e))
__global__ void softmax_cam(const float* __restrict__ E, u16* __restrict__ attn) {
  __shared__ float sm[4];
  const long long r = blockIdx.x;  // 8192 rows of 512
  const float* e = E + r * 512;
  int tid = threadIdx.x, wave = tid >> 6, lane = tid & 63;
  float v0 = e[tid], v1 = e[tid + 256];
  float mn = fminf(v0, v1);
#pragma unroll
  for (int o = 32; o; o >>= 1) mn = fminf(mn, __shfl_xor(mn, o));
  if (lane == 0) sm[wave] = mn;
  __syncthreads();
  mn = fminf(fminf(sm[0], sm[1]), fminf(sm[2], sm[3]));
  float p0 = __expf(mn - v0), p1 = __expf(mn - v1);
  float s = p0 + p1;
#pragma unroll
  for (int o = 32; o; o >>= 1) s += __shfl_xor(s, o);
  __syncthreads();
  if (lane == 0) sm[wave] = s;
  __syncthreads();
  float inv = 1.f / (sm[0] + sm[1] + sm[2] + sm[3]);
  attn[r * 512 + tid] = f2h(p0 * inv);
  attn[r * 512 + tid + 256] = f2h(p1 * inv);
}

// PAM row-sum: EP holds exp(e-4) fp16 (written by energy_p EPI=5).
// inv[r] = 1 / sum_n EP[r][n].  Applied in out_p's epilogue (EPI=6).
__global__ void rowsum_inv(const u16* __restrict__ EP, float* __restrict__ inv) {
  __shared__ float sm[4];
  const long long r = blockIdx.x;  // 18432 rows
  const u16* e = EP + r * 2304;
  int tid = threadIdx.x, wave = tid >> 6, lane = tid & 63;
  u16x8 m8 = *(const u16x8*)&e[tid * 8];
  float s = 0.f;
#pragma unroll
  for (int k = 0; k < 8; k++) s += h2f(m8[k]);
  if (tid < 32) {
    u16x8 t8 = *(const u16x8*)&e[2048 + tid * 8];
#pragma unroll
    for (int k = 0; k < 8; k++) s += h2f(t8[k]);
  }
#pragma unroll
  for (int o = 32; o; o >>= 1) s += __shfl_xor(s, o);
  if (lane == 0) sm[wave] = s;
  __syncthreads();
  if (tid == 0) inv[r] = 1.f / (sm[0] + sm[1] + sm[2] + sm[3]);
}

// ---------------------------------------------------------------------------
extern "C" void kernel_launch(void* const* d_in, const int* in_sizes, int n_in,
                              void* d_out, int out_size, void* d_ws, size_t ws_size,
                              hipStream_t stream) {
  const float* x   = (const float*)d_in[0];
  const float* Wqc = (const float*)d_in[1];
  const float* bqc = (const float*)d_in[2];
  const float* Wkc = (const float*)d_in[3];
  const float* bkc = (const float*)d_in[4];
  const float* Wqp = (const float*)d_in[5];
  const float* bqp = (const float*)d_in[6];
  const float* Wkp = (const float*)d_in[7];
  const float* bkp = (const float*)d_in[8];
  float* outc = (float*)d_out;                 // (8,1024,2304) fp32
  float* outp = outc + 8LL * 1024 * 2304;      // (8,1024,48,48) fp32

  if (ws_size < 195166208ULL) return;  // need ~186.1 MB scratch

  char* ws = (char*)d_ws;
  // lifetime-aliased arena (fp16 buffers as u16):
  u16*   P    = (u16*)(ws + 0);             // 4608x4608       [dead after conv]
  u16*   Wh   = (u16*)(ws + 42467328LL);    // 1536x4608 hi    [dead after conv]
  u16*   Wl   = (u16*)(ws + 56623104LL);    // 1536x4608 lo    [dead after conv]
  u16*   EP   = (u16*)(ws + 0);             // 8x2304x2304     [aliases P+W]
  u16*   qcth = (u16*)(ws + 84934656LL);    // 1536x4608 hi    [dead after energy]
  u16*   qctl = (u16*)(ws + 99090432LL);    // 1536x4608 lo    [dead after energy]
  u16*   pp   = (u16*)(ws + 84934656LL);    // 18432x128       [aliases qct]
  float* E    = (float*)(ws + 113246208LL); // 8x1024x512 fp32 [dead after softmax_cam]
  float* inv  = (float*)(ws + 113246208LL); // 18432 fp32      [aliases dead E]
  u16*   attn = (u16*)(ws + 130023424LL);   // 8x1024x512      [till out_p2]
  u16*   xt   = (u16*)(ws + 138412032LL);   // 18432x512       [dead after pp gemm]
  u16*   xh   = (u16*)(ws + 157286400LL);   // 8x512x2304      [old ocb slot, lower half]
  u16*   Yt   = (u16*)(ws + 176160768LL);   // 8x2304x512      [old ocb slot, upper half]
  u16*   Wp   = (u16*)(ws + 195035136LL);   // 128x512

  // prep (xt must precede im2col: im2col copies from xt)
  xt_kernel<<<dim3(72, 16, 8), 256, 0, stream>>>(x, xt, xh);
  wprep_kernel<<<3712, 256, 0, stream>>>(Wqc, Wkc, Wh, Wl, Wqp, Wkp, Wp);
  im2col_kernel<<<10368, 256, 0, stream>>>(xt, P);

  // CAM convs (W-split 2-term): qct[ch][(b,sp)] = (Wh+Wl)*P^T + bias,
  // split2-fp16 out.  L3-resident -> NBUF=2 (48KB LDS)
  gemm_bt<2, true, false, 1><<<dim3(36, 12, 1), 256, 0, stream>>>(
      Wh, Wl, P, nullptr, nullptr, qcth, qctl, bqc, bkc, 1024,
      4608, 4608, 4608, 4608, 0, 0, 0);

  // energy[b][q][c] fp32 (3-term: hh + lh + hl)
  gemm_bt<3, true, true, 0><<<dim3(4, 8, 8), 256, 0, stream>>>(
      qcth, qctl, qcth + 1024LL * 4608, qctl + 1024LL * 4608,
      E, nullptr, nullptr,
      nullptr, nullptr, 0, 576, 4608, 4608, 512, 576, 576, 524288);

  softmax_cam<<<8192, 256, 0, stream>>>(E, attn);

  // out_c[b][q][sp] = attn @ x  (fp32 -> d_out only; fp16 copy no longer
  // needed -- PAM PV reassociated to use attn directly)
  gemm_bt<3, false, false, 0><<<dim3(18, 8, 8), 256, 0, stream>>>(
      attn, nullptr, xt, nullptr, outc, nullptr, nullptr,
      nullptr, nullptr, 0, 512, 512, 512, 2304, 524288, 1179648, 2359296);

  // qp/kp 1x1 convs: pp[(b,sp)][dd] = xt @ Wp^T + bias(dd)
  gemm_bt<2, false, false, 3><<<dim3(1, 144, 1), 256, 0, stream>>>(
      xt, nullptr, Wp, nullptr, nullptr, pp, nullptr,
      bqp, bkp, 64, 512, 512, 512, 128, 0, 0, 0);

  // energy_p[b][i][j] = qp(i).kp(j), K=64 -> stores exp(e-4) fp16 (EPI=5)
  gemm_bt<3, false, false, 5><<<dim3(18, 18, 8), 256, 0, stream>>>(
      pp, nullptr, pp + 64, nullptr, nullptr, EP, nullptr,
      nullptr, nullptr, 0, 64, 128, 128, 2304, 294912, 294912, 5308416);

  // softmax denominators
  rowsum_inv<<<18432, 256, 0, stream>>>(EP, inv);

  // --- reassociated PAM PV:  out_p = attn @ (x @ EP^T) * inv ---
  // Yt[b][m][c] = sum_n EP[m][n] * xh[c][n]   (fp16 out, 43.5 GFLOP
  // vs 87 GFLOP of the direct ocb @ EP^T -- 28% fewer FLOPs total)
  gemm_bt<3, false, false, 4><<<dim3(4, 18, 8), 256, 0, stream>>>(
      EP, nullptr, xh, nullptr, nullptr, Yt, nullptr,
      nullptr, nullptr, 0, 2304, 2304, 2304, 512, 5308416, 1179648, 1179648);

  // out_p[b][q][m] = (sum_c attn[q][c] * Yt[m][c]) * inv[b*2304+m]  (EPI=6)
  gemm_bt<3, false, false, 6><<<dim3(18, 8, 8), 256, 0, stream>>>(
      attn, nullptr, Yt, nullptr, outp, nullptr, nullptr,
      inv, nullptr, 2304, 512, 512, 512, 2304, 524288, 1179648, 2359296);

  (void)in_sizes; (void)n_in; (void)out_size;
}

// Round 11
// 549.176 us; speedup vs baseline: 1.1739x; 1.0200x over previous
//
#include <hip/hip_runtime.h>
#include <hip/hip_bf16.h>

typedef unsigned short u16;
typedef __attribute__((ext_vector_type(8))) _Float16 half8;  // 8 fp16 in 4 VGPRs
typedef __attribute__((ext_vector_type(8))) unsigned short u16x8;
typedef __attribute__((ext_vector_type(4))) float f32x4;

static __device__ __forceinline__ u16 f2h(float v) {
  return __builtin_bit_cast(u16, (_Float16)v);
}
static __device__ __forceinline__ float h2f(u16 u) {
  return (float)__builtin_bit_cast(_Float16, u);
}

// async global->LDS, 16B per lane. LDS dest = wave-uniform base + lane*16;
// the GLOBAL source address is per-lane (divergent redirect is legal).
static __device__ __forceinline__ void gll16(const void* g, void* l) {
  __builtin_amdgcn_global_load_lds(
      (const __attribute__((address_space(1))) unsigned int*)g,
      (__attribute__((address_space(3))) unsigned int*)l, 16, 0, 0);
}

template <int N>
static __device__ __forceinline__ void wait_vm() {
  if constexpr (N == 0) asm volatile("s_waitcnt vmcnt(0)" ::: "memory");
  else if constexpr (N == 4) asm volatile("s_waitcnt vmcnt(4)" ::: "memory");
  else if constexpr (N == 6) asm volatile("s_waitcnt vmcnt(6)" ::: "memory");
  else asm volatile("s_waitcnt vmcnt(8)" ::: "memory");
}

// ---------------------------------------------------------------------------
// gemm_bt: C[m][n] = sum_k A[m][k] * B[n][k]  (both K-contiguous, fp16).
// 128x128 tile, BK=32, 4 waves (2x2), wave tile 64x64, 16x16x32 MFMA.
// [r7 ERRATA: 32x32x16 MFMA variant tripled LDS bank conflicts and cost
//  +34us on conv. 16x16 form is the measured optimum.]
// NBUF=2: classic double-buffer, vmcnt(0) + barrier each K-step (L2/L3-
//   resident operands). NBUF=3: prefetch-depth 2, COUNTED vmcnt (T4) for
//   HBM-latency-bound z>1 GEMMs. XCD-chunked swizzle only when z>1.
// IMCOL (r11): B operand is the stride-2 3x3 pad-1 im2col of xt, read
//   DIRECTLY (no materialized P). For a BK=32 window, g=ko>>9 is block-
//   uniform, so the source row is xt[(b, iy*48+ix)] with iy/ix from the
//   per-lane (oy,ox) and block-uniform (ky,kx); OOB rows -> 16B zero page
//   (Bl). Same 16B/lane contiguity as before; only the row pointer moves.
// ASPLIT: A given as hi+lo fp16; adds term Al*B.
// BSPLIT: B given as hi+lo fp16; adds term A*Bl. (ll dropped, ~2^-22)
// EPI: 0 = fp32 store; 1 = bias(m) + split2-fp16 store (Ch,Cl);
//      2 = fp32 + fp16 store; 3 = bias(n) + fp16 store; 4 = fp16 store;
//      5 = fp16 store of exp(v-4) + per-row partial sums -> Cf=Spart
//          [(z*2304+gm)*36 + bx*2 + wc]  (fused PAM softmax denominator);
//      6 = fp32 store of v * bias0[z*biasSplit + gn]
// ---------------------------------------------------------------------------
template <int NBUF, bool ASPLIT, bool BSPLIT, bool IMCOL, int EPI>
__global__ __launch_bounds__(256) void gemm_bt(
    const u16* __restrict__ A, const u16* __restrict__ Al,
    const u16* __restrict__ B, const u16* __restrict__ Bl,
    float* __restrict__ Cf, u16* __restrict__ Ch, u16* __restrict__ Cl,
    const float* __restrict__ bias0, const float* __restrict__ bias1,
    int biasSplit, int K, int lda, int ldb, int ldc,
    long long sA, long long sB, long long sC) {
  __shared__ __align__(16) u16 smA[NBUF][(ASPLIT ? 2 : 1) * 128 * 32];
  __shared__ __align__(16) u16 smB[NBUF][(BSPLIT ? 2 : 1) * 128 * 32];
  constexpr int G = 4 + (ASPLIT ? 2 : 0) + (BSPLIT ? 2 : 0);  // loads per stage
  constexpr int PD = NBUF - 1;                                 // prefetch depth

  const int tid = threadIdx.x;
  const int wave = tid >> 6, lane = tid & 63;
  const int wr = wave >> 1, wc = wave & 1;

  const int gx = gridDim.x, gy = gridDim.y;
  int bx, by;
  long long z;
  if (gridDim.z > 1) {
    const int nwg = gx * gy * (int)gridDim.z;
    const int bid = (int)blockIdx.x + gx * ((int)blockIdx.y + gy * (int)blockIdx.z);
    const int w = (bid & 7) * (nwg >> 3) + (bid >> 3);
    bx = w % gx;
    const int rem = w / gx;
    by = rem % gy;
    z = rem / gy;
  } else {
    bx = blockIdx.x;
    by = blockIdx.y;
    z = 0;
  }

  A += z * sA;
  B += z * sB;
  if (ASPLIT) Al += z * sA;
  if (BSPLIT) Bl += z * sB;
  const long long tM = (long long)by * 128;
  const long long tN = (long long)bx * 128;
  const int r4 = lane >> 2, kc = lane & 3;

  const long long arow0 = (tM + wave * 16 + r4) * (long long)lda + kc * 8;
  const long long arow1 = arow0 + 64LL * lda;

  long long brow0 = 0, brow1 = 0;
  int spb0 = 0, oy20 = 0, ox20 = 0, spb1 = 0, oy21 = 0, ox21 = 0;
  if constexpr (IMCOL) {
    const int n0 = (int)tN + wave * 16 + r4;
    const int b0 = n0 / 576, t0 = n0 - b0 * 576;
    const int oy0 = t0 / 24, ox0 = t0 - oy0 * 24;
    spb0 = b0 * 2304; oy20 = 2 * oy0 - 1; ox20 = 2 * ox0 - 1;
    const int n1 = n0 + 64;
    const int b1 = n1 / 576, t1 = n1 - b1 * 576;
    const int oy1 = t1 / 24, ox1 = t1 - oy1 * 24;
    spb1 = b1 * 2304; oy21 = 2 * oy1 - 1; ox21 = 2 * ox1 - 1;
  } else {
    brow0 = (tN + wave * 16 + r4) * (long long)ldb + kc * 8;
    brow1 = brow0 + 64LL * ldb;
  }

  auto stage = [&](int bf, long long ko) {
    u16* dA = &smA[bf][wave * 512];
    u16* dB = &smB[bf][wave * 512];
    gll16(A + arow0 + ko, dA);
    gll16(A + arow1 + ko, dA + 2048);
    if constexpr (IMCOL) {
      const int koi = (int)ko;
      const int g = koi >> 9;
      const int ky = g / 3, kx = g - ky * 3;
      const int co = (koi & 511) + kc * 8;
      const int iy0 = oy20 + ky, ix0 = ox20 + kx;
      const u16* s0 = ((unsigned)iy0 < 48u && (unsigned)ix0 < 48u)
          ? B + (((long long)(spb0 + iy0 * 48 + ix0)) << 9) + co : Bl;
      gll16(s0, dB);
      const int iy1 = oy21 + ky, ix1 = ox21 + kx;
      const u16* s1 = ((unsigned)iy1 < 48u && (unsigned)ix1 < 48u)
          ? B + (((long long)(spb1 + iy1 * 48 + ix1)) << 9) + co : Bl;
      gll16(s1, dB + 2048);
    } else {
      gll16(B + brow0 + ko, dB);
      gll16(B + brow1 + ko, dB + 2048);
    }
    if constexpr (ASPLIT) {
      gll16(Al + arow0 + ko, dA + 4096);
      gll16(Al + arow1 + ko, dA + 4096 + 2048);
    }
    if constexpr (BSPLIT) {
      gll16(Bl + brow0 + ko, dB + 4096);
      gll16(Bl + brow1 + ko, dB + 4096 + 2048);
    }
  };

  f32x4 acc[4][4];
#pragma unroll
  for (int i = 0; i < 4; i++)
#pragma unroll
    for (int j = 0; j < 4; j++) acc[i][j] = f32x4{0.f, 0.f, 0.f, 0.f};

  const int quad = lane >> 4, mr = lane & 15;
  const int nk = K >> 5;

  stage(0, 0);
  if constexpr (PD == 2) {
    if (nk > 1) stage(1, 32);
  }

  int cur = 0;
  for (int kt = 0; kt < nk; ++kt) {
    if (PD == 2 && kt < nk - 1) wait_vm<G>(); else wait_vm<0>();
    __builtin_amdgcn_s_barrier();
    asm volatile("" ::: "memory");  // keep LDS reads below the barrier

    half8 a[4], b[4];
#pragma unroll
    for (int i = 0; i < 4; i++)
      a[i] = *(const half8*)&smA[cur][(wr * 64 + i * 16 + mr) * 32 + quad * 8];
#pragma unroll
    for (int j = 0; j < 4; j++)
      b[j] = *(const half8*)&smB[cur][(wc * 64 + j * 16 + mr) * 32 + quad * 8];

    if (kt + PD < nk) {
      int pf = cur + PD; if (pf >= NBUF) pf -= NBUF;
      stage(pf, (long long)(kt + PD) * 32);
    }

#pragma unroll
    for (int i = 0; i < 4; i++)
#pragma unroll
      for (int j = 0; j < 4; j++)
        acc[i][j] = __builtin_amdgcn_mfma_f32_16x16x32_f16(a[i], b[j], acc[i][j], 0, 0, 0);

    if constexpr (ASPLIT) {
      half8 al[4];
#pragma unroll
      for (int i = 0; i < 4; i++)
        al[i] = *(const half8*)&smA[cur][4096 + (wr * 64 + i * 16 + mr) * 32 + quad * 8];
#pragma unroll
      for (int i = 0; i < 4; i++)
#pragma unroll
        for (int j = 0; j < 4; j++)
          acc[i][j] = __builtin_amdgcn_mfma_f32_16x16x32_f16(al[i], b[j], acc[i][j], 0, 0, 0);
    }
    if constexpr (BSPLIT) {
      half8 bl[4];
#pragma unroll
      for (int j = 0; j < 4; j++)
        bl[j] = *(const half8*)&smB[cur][4096 + (wc * 64 + j * 16 + mr) * 32 + quad * 8];
#pragma unroll
      for (int i = 0; i < 4; i++)
#pragma unroll
        for (int j = 0; j < 4; j++)
          acc[i][j] = __builtin_amdgcn_mfma_f32_16x16x32_f16(a[i], bl[j], acc[i][j], 0, 0, 0);
    }
    cur = (cur == NBUF - 1) ? 0 : cur + 1;
  }

  // epilogue: C/D map (verified): col = lane&15, row = quad*4 + reg
  if constexpr (EPI == 5) {
    // exp store + fused row-partial sums (PAM softmax denominator).
#pragma unroll
    for (int i = 0; i < 4; i++) {
      float rp[4] = {0.f, 0.f, 0.f, 0.f};
#pragma unroll
      for (int j = 0; j < 4; j++) {
        const long long gn = tN + wc * 64 + j * 16 + mr;
#pragma unroll
        for (int p = 0; p < 4; p++) {
          const long long gm = tM + wr * 64 + i * 16 + quad * 4 + p;
          const float ev = __expf(acc[i][j][p] - 4.0f);
          Ch[z * sC + gm * ldc + gn] = f2h(ev);
          rp[p] += ev;
        }
      }
      // reduce across the 16-lane mr group (lane bits 0-3)
#pragma unroll
      for (int p = 0; p < 4; p++)
#pragma unroll
        for (int o = 8; o; o >>= 1) rp[p] += __shfl_xor(rp[p], o);
      if (mr == 0) {
#pragma unroll
        for (int p = 0; p < 4; p++) {
          const long long gm = tM + wr * 64 + i * 16 + quad * 4 + p;
          Cf[(z * 2304 + gm) * 36 + bx * 2 + wc] = rp[p];
        }
      }
    }
  } else {
#pragma unroll
    for (int i = 0; i < 4; i++) {
#pragma unroll
      for (int j = 0; j < 4; j++) {
        const long long gn = tN + wc * 64 + j * 16 + mr;
#pragma unroll
        for (int p = 0; p < 4; p++) {
          const long long gm = tM + wr * 64 + i * 16 + quad * 4 + p;
          float v = acc[i][j][p];
          if constexpr (EPI == 1) v += (gm < biasSplit) ? bias0[gm] : bias1[gm - biasSplit];
          if constexpr (EPI == 3) v += (gn < biasSplit) ? bias0[gn] : bias1[gn - biasSplit];
          if constexpr (EPI == 6) v *= bias0[z * biasSplit + gn];
          const long long off = z * sC + gm * ldc + gn;
          if constexpr (EPI == 0 || EPI == 6) {
            Cf[off] = v;
          } else if constexpr (EPI == 1) {
            u16 h = f2h(v);
            Ch[off] = h;
            Cl[off] = f2h(v - h2f(h));
          } else if constexpr (EPI == 2) {
            Cf[off] = v;
            Ch[off] = f2h(v);
          } else {
            Ch[off] = f2h(v);
          }
        }
      }
    }
  }
  (void)biasSplit;
}

// W split2-fp16 in the permuted k' = g*512 + c layout; blocks 3456-3711
// handle Wqp/Wkp -> Wp; block 3712 writes the 16B zero page for IMCOL.
__global__ void wprep_kernel(const float* __restrict__ Wqc, const float* __restrict__ Wkc,
                             u16* __restrict__ Wh, u16* __restrict__ Wl,
                             const float* __restrict__ Wqp, const float* __restrict__ Wkp,
                             u16* __restrict__ Wp, u16* __restrict__ zp) {
  if (blockIdx.x == 3712) {
    if (threadIdx.x < 32) zp[threadIdx.x] = 0;
    return;
  }
  if (blockIdx.x >= 3456) {
    int idx = (blockIdx.x - 3456) * 256 + threadIdx.x;  // < 128*512 = 65536
    int d = idx >> 9;
    float v = (d < 64) ? Wqp[idx] : Wkp[idx - 64 * 512];
    Wp[idx] = f2h(v);
    return;
  }
  int idx = blockIdx.x * 256 + threadIdx.x;  // < 1536*576 = 884736
  int n = idx / 576;
  int r = idx - n * 576;
  int g = r >> 6;
  int c0 = (r & 63) * 8;
  const float* src = (n < 1024)
      ? &Wqc[((long long)n * 512 + c0) * 9 + g]
      : &Wkc[(((long long)n - 1024) * 512 + c0) * 9 + g];
  u16x8 h8, l8;
#pragma unroll
  for (int j = 0; j < 8; j++) {
    float v = src[j * 9];
    u16 h = f2h(v);
    h8[j] = h;
    l8[j] = f2h(v - h2f(h));
  }
  long long out = (long long)n * 4608 + (long long)g * 512 + c0;
  *(u16x8*)&Wh[out] = h8;
  *(u16x8*)&Wl[out] = l8;
}

// x (b,c,sp) -> xt[(b,sp)][c] fp16 (tiled transpose) AND xh[(b,c)][sp] fp16.
__global__ void xt_kernel(const float* __restrict__ x, u16* __restrict__ xt,
                          u16* __restrict__ xh) {
  __shared__ float t[32][33];
  int b = blockIdx.z;
  int sp0 = blockIdx.x * 32, c0 = blockIdx.y * 32;
  int tx = threadIdx.x & 31, ty = threadIdx.x >> 5;  // 32 x 8
#pragma unroll
  for (int k = 0; k < 4; k++) {
    int c = c0 + ty + k * 8;
    long long src = ((long long)(b * 512 + c)) * 2304 + sp0 + tx;
    float v = x[src];
    t[ty + k * 8][tx] = v;
    xh[src] = f2h(v);
  }
  __syncthreads();
#pragma unroll
  for (int k = 0; k < 4; k++) {
    int sp = sp0 + ty + k * 8;
    xt[((long long)b * 2304 + sp) * 512 + c0 + tx] = f2h(t[tx][ty + k * 8]);
  }
}

// CAM softmax: attn = exp(rowmin - e)/sum  (== softmax(rowmax - e))
__global__ void softmax_cam(const float* __restrict__ E, u16* __restrict__ attn) {
  __shared__ float sm[4];
  const long long r = blockIdx.x;  // 8192 rows of 512
  const float* e = E + r * 512;
  int tid = threadIdx.x, wave = tid >> 6, lane = tid & 63;
  float v0 = e[tid], v1 = e[tid + 256];
  float mn = fminf(v0, v1);
#pragma unroll
  for (int o = 32; o; o >>= 1) mn = fminf(mn, __shfl_xor(mn, o));
  if (lane == 0) sm[wave] = mn;
  __syncthreads();
  mn = fminf(fminf(sm[0], sm[1]), fminf(sm[2], sm[3]));
  float p0 = __expf(mn - v0), p1 = __expf(mn - v1);
  float s = p0 + p1;
#pragma unroll
  for (int o = 32; o; o >>= 1) s += __shfl_xor(s, o);
  __syncthreads();
  if (lane == 0) sm[wave] = s;
  __syncthreads();
  float inv = 1.f / (sm[0] + sm[1] + sm[2] + sm[3]);
  attn[r * 512 + tid] = f2h(p0 * inv);
  attn[r * 512 + tid + 256] = f2h(p1 * inv);
}

// inv[r] = 1 / sum of the 36 block-partials written by energy_p's epilogue.
__global__ void inv_from_S(const float* __restrict__ Sp, float* __restrict__ inv) {
  int r = blockIdx.x * 256 + threadIdx.x;  // 18432
  const float* p = Sp + (long long)r * 36;
  float s = 0.f;
#pragma unroll
  for (int k = 0; k < 36; k++) s += p[k];
  inv[r] = 1.f / s;
}

// ---------------------------------------------------------------------------
extern "C" void kernel_launch(void* const* d_in, const int* in_sizes, int n_in,
                              void* d_out, int out_size, void* d_ws, size_t ws_size,
                              hipStream_t stream) {
  const float* x   = (const float*)d_in[0];
  const float* Wqc = (const float*)d_in[1];
  const float* bqc = (const float*)d_in[2];
  const float* Wkc = (const float*)d_in[3];
  const float* bkc = (const float*)d_in[4];
  const float* Wqp = (const float*)d_in[5];
  const float* bqp = (const float*)d_in[6];
  const float* Wkp = (const float*)d_in[7];
  const float* bkp = (const float*)d_in[8];
  float* outc = (float*)d_out;                 // (8,1024,2304) fp32
  float* outp = outc + 8LL * 1024 * 2304;      // (8,1024,48,48) fp32

  if (ws_size < 195166208ULL) return;  // need ~186.1 MB scratch

  char* ws = (char*)d_ws;
  // lifetime-aliased arena (fp16 buffers as u16):
  u16*   Wh   = (u16*)(ws + 42467328LL);    // 1536x4608 hi    [dead after conv]
  u16*   Wl   = (u16*)(ws + 56623104LL);    // 1536x4608 lo    [dead after conv]
  u16*   EP   = (u16*)(ws + 0);             // 8x2304x2304     [P slot freed by IMCOL]
  u16*   qcth = (u16*)(ws + 84934656LL);    // 1536x4608 hi    [dead after energy]
  u16*   qctl = (u16*)(ws + 99090432LL);    // 1536x4608 lo    [dead after energy]
  u16*   pp   = (u16*)(ws + 84934656LL);    // 18432x128       [aliases qct]
  u16*   zp   = (u16*)(ws + 113246208LL);   // 16B zero page   [dead after conv; E overwrites]
  float* E    = (float*)(ws + 113246208LL); // 8x1024x512 fp32 [dead after softmax_cam]
  float* inv  = (float*)(ws + 113246208LL); // 18432 fp32      [aliases dead E]
  u16*   attn = (u16*)(ws + 130023424LL);   // 8x1024x512      [till out_p2]
  u16*   xt   = (u16*)(ws + 138412032LL);   // 18432x512       [dead after pp gemm]
  float* Spart= (float*)(ws + 138412032LL); // 18432x36 fp32   [aliases dead xt]
  u16*   xh   = (u16*)(ws + 157286400LL);   // 8x512x2304
  u16*   Yt   = (u16*)(ws + 176160768LL);   // 8x2304x512
  u16*   Wp   = (u16*)(ws + 195035136LL);   // 128x512

  // prep
  xt_kernel<<<dim3(72, 16, 8), 256, 0, stream>>>(x, xt, xh);
  wprep_kernel<<<3713, 256, 0, stream>>>(Wqc, Wkc, Wh, Wl, Wqp, Wkp, Wp, zp);

  // CAM convs (W-split 2-term, IMPLICIT im2col: B read straight from xt,
  // OOB rows -> zero page). split2-fp16 out. NBUF=2 (48KB LDS).
  gemm_bt<2, true, false, true, 1><<<dim3(36, 12, 1), 256, 0, stream>>>(
      Wh, Wl, xt, zp, nullptr, qcth, qctl, bqc, bkc, 1024,
      4608, 4608, 512, 4608, 0, 0, 0);

  // energy[b][q][c] fp32 (3-term: hh + lh + hl)
  gemm_bt<3, true, true, false, 0><<<dim3(4, 8, 8), 256, 0, stream>>>(
      qcth, qctl, qcth + 1024LL * 4608, qctl + 1024LL * 4608,
      E, nullptr, nullptr,
      nullptr, nullptr, 0, 576, 4608, 4608, 512, 576, 576, 524288);

  softmax_cam<<<8192, 256, 0, stream>>>(E, attn);

  // out_c[b][q][sp] = attn @ x  (fp32 -> d_out)
  gemm_bt<3, false, false, false, 0><<<dim3(18, 8, 8), 256, 0, stream>>>(
      attn, nullptr, xt, nullptr, outc, nullptr, nullptr,
      nullptr, nullptr, 0, 512, 512, 512, 2304, 524288, 1179648, 2359296);

  // qp/kp 1x1 convs: pp[(b,sp)][dd] = xt @ Wp^T + bias(dd)
  gemm_bt<2, false, false, false, 3><<<dim3(1, 144, 1), 256, 0, stream>>>(
      xt, nullptr, Wp, nullptr, nullptr, pp, nullptr,
      bqp, bkp, 64, 512, 512, 512, 128, 0, 0, 0);

  // energy_p: stores exp(e-4) fp16 + fused row-partial sums -> Spart (EPI=5)
  gemm_bt<3, false, false, false, 5><<<dim3(18, 18, 8), 256, 0, stream>>>(
      pp, nullptr, pp + 64, nullptr, Spart, EP, nullptr,
      nullptr, nullptr, 0, 64, 128, 128, 2304, 294912, 294912, 5308416);

  // softmax denominators from the fused partials (72KB out)
  inv_from_S<<<72, 256, 0, stream>>>(Spart, inv);

  // reassociated PAM PV:  out_p = attn @ (x @ EP^T) * inv
  // Yt[b][m][c] = sum_n EP[m][n] * xh[c][n]
  gemm_bt<3, false, false, false, 4><<<dim3(4, 18, 8), 256, 0, stream>>>(
      EP, nullptr, xh, nullptr, nullptr, Yt, nullptr,
      nullptr, nullptr, 0, 2304, 2304, 2304, 512, 5308416, 1179648, 1179648);

  // out_p[b][q][m] = (sum_c attn[q][c] * Yt[m][c]) * inv[b*2304+m]  (EPI=6)
  gemm_bt<3, false, false, false, 6><<<dim3(18, 8, 8), 256, 0, stream>>>(
      attn, nullptr, Yt, nullptr, outp, nullptr, nullptr,
      inv, nullptr, 2304, 512, 512, 512, 2304, 524288, 1179648, 2359296);

  (void)in_sizes; (void)n_in; (void)out_size;
}